// Round 14
// baseline (111.613 us; speedup 1.0000x reference)
//
#include <hip/hip_runtime.h>
#include <hip/hip_bf16.h>
#include <hip/hip_fp16.h>

#define BB 4
#define SS 2048
#define DD 512

typedef short s16x8 __attribute__((ext_vector_type(8)));
typedef short s16x4 __attribute__((ext_vector_type(4)));
typedef float f32x4 __attribute__((ext_vector_type(4)));
typedef _Float16 f16x8 __attribute__((ext_vector_type(8)));

__device__ __forceinline__ short f2h(float f) {
    const _Float16 h = (_Float16)f;
    union { _Float16 h; short s; } u; u.h = h; return u.s;
}
__device__ __forceinline__ float h2f(short s) {
    union { short s; _Float16 h; } u; u.s = s; return (float)u.h;
}
__device__ __forceinline__ f16x8 as_h(s16x8 v) {
    union { s16x8 s; f16x8 h; } u; u.s = v; return u.h;
}

__device__ __forceinline__ void gload_lds16(const void* g, void* l) {
    __builtin_amdgcn_global_load_lds(
        (const __attribute__((address_space(1))) void*)g,
        (__attribute__((address_space(3))) void*)l, 16, 0, 0);
}

#define SB0 __builtin_amdgcn_sched_barrier(0)
#define LGKM0 asm volatile("s_waitcnt lgkmcnt(0)" ::: "memory")
#define VM0   asm volatile("s_waitcnt vmcnt(0)" ::: "memory")

// ---------------------------------------------------------------------------
// QK^T 256x256, BK=32, 8 waves, fp16, XCD swizzle, single-phase-per-tile
// (R12-proven). int16 scores via LDS repack + per-block row softmax stats
// (max, sumexp) via 32-lane shfl reduce -> rowstat[z][bn/256][row].
// ---------------------------------------------------------------------------
__global__ __launch_bounds__(512, 2) void qkt256(
    const short* __restrict__ qf, const short* __restrict__ kf,
    short* __restrict__ outS, float2* __restrict__ rowstat, int nwg)
{
    __shared__ short lds[65536];

    const int tid = threadIdx.x;
    const int wave = tid >> 6, lane = tid & 63;
    const int flat = blockIdx.x + 8 * blockIdx.y + 64 * blockIdx.z;
    const int w = (flat & 7) * (nwg >> 3) + (flat >> 3);
    const int bm = ((w >> 3) & 7) * 256, bn = (w & 7) * 256;
    const long z = w >> 6;
    qf += z * (long)SS * DD; kf += z * (long)SS * DD;
    outS += z * (long)SS * SS;
    rowstat += z * 8 * SS;

    const int wm = (wave >> 2) * 128, wn = (wave & 3) * 64;
    const int lrow = lane & 15, lk16 = (lane >> 4) * 16;

    f32x4 acc[8][4] = {};

    auto base = [&](int buf, int arr) -> short* { return &lds[(buf * 2 + arr) * 8192]; };
    auto issue = [&](int buf, int arr, int k0) {
#pragma unroll
        for (int h = 0; h < 2; h++) {
            const int Lb = (h << 13) + (tid << 4);
            const int Ls = Lb ^ (((Lb >> 7) & 3) << 4);
            const int row = Ls >> 6, elem = (Ls & 63) >> 1;
            const short* s = arr ? kf : qf;
            const int rb = arr ? bn : bm;
            gload_lds16(s + (size_t)(rb + row) * DD + k0 + elem,
                        (char*)base(buf, arr) + Lb);
        }
    };
    auto rd = [&](int buf, int arr, int row) -> s16x8 {
        const int L = (row << 6) + lk16;
        const int Ls = L ^ (((L >> 7) & 3) << 4);
        return *(const s16x8*)((const char*)base(buf, arr) + Ls);
    };

#define QK_TILE(T, CUR, PREF)                                                    \
  {                                                                              \
    s16x8 a[8], b[4];                                                            \
    _Pragma("unroll")                                                            \
    for (int m = 0; m < 8; m++) a[m] = rd(CUR, 0, wm + m * 16 + lrow);           \
    _Pragma("unroll")                                                            \
    for (int n = 0; n < 4; n++) b[n] = rd(CUR, 1, wn + n * 16 + lrow);           \
    if (PREF) { issue((CUR) ^ 1, 1, ((T) + 1) * 32); SB0;                        \
                issue((CUR) ^ 1, 0, ((T) + 1) * 32); }                           \
    LGKM0; SB0;                                                                  \
    __builtin_amdgcn_s_setprio(1);                                               \
    _Pragma("unroll")                                                            \
    for (int m = 0; m < 8; m++) {                                                \
      _Pragma("unroll")                                                          \
      for (int n = 0; n < 4; n++)                                                \
        acc[m][n] = __builtin_amdgcn_mfma_f32_16x16x32_f16(                      \
            as_h(a[m]), as_h(b[n]), acc[m][n], 0, 0, 0);                         \
    }                                                                            \
    __builtin_amdgcn_s_setprio(0);                                               \
    if (PREF) { VM0; SB0; }                                                      \
    __builtin_amdgcn_s_barrier();                                                \
  }

    issue(0, 1, 0); issue(0, 0, 0);
    VM0;
    __builtin_amdgcn_s_barrier();

    for (int t = 0; t < 16; t += 2) {
        QK_TILE(t,     0, 1);
        QK_TILE(t + 1, 1, (t + 1) < 15);
    }
#undef QK_TILE

    __syncthreads();
    short* ebuf = &lds[0];
#pragma unroll
    for (int m = 0; m < 8; m++) {
#pragma unroll
        for (int n = 0; n < 4; n++) {
#pragma unroll
            for (int j = 0; j < 4; j++) {
                const int rl = wm + m * 16 + (lane >> 4) * 4 + j;
                const int cl = wn + n * 16 + lrow;
                const int pcb = (cl >> 3) ^ ((rl & 3) << 1);
                ebuf[rl * 256 + pcb * 8 + (cl & 7)] =
                    (short)__float2int_rn(acc[m][n][j] * 128.0f);
            }
        }
    }
    __syncthreads();
    // store + per-block row (max, sumexp): 32 threads share a row
#pragma unroll
    for (int it = 0; it < 16; it++) {
        const int u = it * 512 + tid;
        const int R = u >> 5, cb = u & 31;
        const int pcb = cb ^ ((R & 3) << 1);
        const s16x8 val = *(const s16x8*)&ebuf[R * 256 + pcb * 8];
        *(s16x8*)&outS[(size_t)(bm + R) * SS + bn + cb * 8] = val;
        float vf[8], vmax = -3e38f;
#pragma unroll
        for (int j = 0; j < 8; j++) {
            vf[j] = (float)(int)val[j] * 0.0078125f;
            vmax = fmaxf(vmax, vf[j]);
        }
#pragma unroll
        for (int off = 1; off <= 16; off <<= 1) vmax = fmaxf(vmax, __shfl_xor(vmax, off));
        float se = 0.f;
#pragma unroll
        for (int j = 0; j < 8; j++) se += __expf(vf[j] - vmax);
#pragma unroll
        for (int off = 1; off <= 16; off <<= 1) se += __shfl_xor(se, off);
        if ((tid & 31) == 0)
            rowstat[(size_t)(bn >> 8) * SS + bm + R] = make_float2(vmax, se);
    }
}

// ---------------------------------------------------------------------------
// Unified projection, all-fp16, single-phase-per-tile + chunked XCD swizzle
// (R13-proven, unchanged).
// ---------------------------------------------------------------------------
__global__ __launch_bounds__(256, 3) void proj_all(
    const short* __restrict__ xh, const short* __restrict__ xl,
    const short* __restrict__ wt,
    const float* __restrict__ bq, const float* __restrict__ bk,
    const float* __restrict__ bv,
    short* __restrict__ qfp, short* __restrict__ kfp, short* __restrict__ vt)
{
    __shared__ short lds[24576];

    const int tid = threadIdx.x;
    const int wave = tid >> 6, lane = tid & 63;
    const int flat = blockIdx.x + 12 * blockIdx.y;
    const int w = (flat & 7) * 96 + (flat >> 3);
    const int bxi = w % 12, byi = w / 12;
    const int wsel = bxi >> 2;
    const int bnl = (bxi & 3) * 128;
    const int bm = byi * 128;
    const bool lo = (wsel < 2);
    const short* B0 = wt + (size_t)wsel * DD * DD;
    const float* bias = (wsel == 0) ? bq : (wsel == 1) ? bk : bv;

    f32x4 acc[4][4] = {};
    const int wm = (wave >> 1) * 64, wn = (wave & 1) * 64;
    const int lrow = lane & 15, lk16 = (lane >> 4) * 16;

    auto base = [&](int buf, int arr) -> short* { return &lds[(buf * 3 + arr) * 4096]; };
    auto issue = [&](int buf, int arr, int k0) {
#pragma unroll
        for (int h = 0; h < 2; h++) {
            const int Lb = (h << 12) + (tid << 4);
            const int Ls = Lb ^ (((Lb >> 7) & 3) << 4);
            const int row = Ls >> 6, elem = (Ls & 63) >> 1;
            const short* s = (arr == 0) ? xh : (arr == 1) ? xl : B0;
            const int rb = (arr < 2) ? bm : bnl;
            gload_lds16(s + (size_t)(rb + row) * DD + k0 + elem,
                        (char*)base(buf, arr) + Lb);
        }
    };
    auto rd = [&](int buf, int arr, int row) -> s16x8 {
        const int L = (row << 6) + lk16;
        const int Ls = L ^ (((L >> 7) & 3) << 4);
        return *(const s16x8*)((const char*)base(buf, arr) + Ls);
    };

#define PJ_TILE(T, CUR, PREF)                                                    \
  {                                                                              \
    s16x8 ah[4], al[4], b[4];                                                    \
    _Pragma("unroll")                                                            \
    for (int m = 0; m < 4; m++) ah[m] = rd(CUR, 0, wm + m * 16 + lrow);          \
    if (lo) {                                                                    \
      _Pragma("unroll")                                                          \
      for (int m = 0; m < 4; m++) al[m] = rd(CUR, 1, wm + m * 16 + lrow);        \
    }                                                                            \
    _Pragma("unroll")                                                            \
    for (int n = 0; n < 4; n++) b[n] = rd(CUR, 2, wn + n * 16 + lrow);           \
    if (PREF) {                                                                  \
      issue((CUR) ^ 1, 2, ((T) + 1) * 32); SB0;                                  \
      issue((CUR) ^ 1, 0, ((T) + 1) * 32);                                       \
      if (lo) issue((CUR) ^ 1, 1, ((T) + 1) * 32);                               \
    }                                                                            \
    LGKM0; SB0;                                                                  \
    __builtin_amdgcn_s_setprio(1);                                               \
    _Pragma("unroll")                                                            \
    for (int m = 0; m < 4; m++) {                                                \
      _Pragma("unroll")                                                          \
      for (int n = 0; n < 4; n++) {                                              \
        acc[m][n] = __builtin_amdgcn_mfma_f32_16x16x32_f16(                      \
            as_h(ah[m]), as_h(b[n]), acc[m][n], 0, 0, 0);                        \
        if (lo)                                                                  \
          acc[m][n] = __builtin_amdgcn_mfma_f32_16x16x32_f16(                    \
              as_h(al[m]), as_h(b[n]), acc[m][n], 0, 0, 0);                      \
      }                                                                          \
    }                                                                            \
    __builtin_amdgcn_s_setprio(0);                                               \
    if (PREF) { VM0; SB0; }                                                      \
    __builtin_amdgcn_s_barrier();                                                \
  }

    issue(0, 2, 0); issue(0, 0, 0);
    if (lo) issue(0, 1, 0);
    VM0;
    __builtin_amdgcn_s_barrier();

    for (int t = 0; t < 16; t += 2) {
        PJ_TILE(t,     0, 1);
        PJ_TILE(t + 1, 1, (t + 1) < 15);
    }
#undef PJ_TILE

    __syncthreads();
    short* cbuf = &lds[0];
#pragma unroll
    for (int m = 0; m < 4; m++) {
#pragma unroll
        for (int n = 0; n < 4; n++) {
#pragma unroll
            for (int j = 0; j < 4; j++) {
                const int rl = wm + m * 16 + (lane >> 4) * 4 + j;
                const int cl = wn + n * 16 + lrow;
                const float v = acc[m][n][j] + bias[bnl + cl];
                if (wsel < 2)
                    cbuf[rl * 128 + (cl ^ ((rl & 7) << 3))] = f2h(v);
                else
                    cbuf[cl * 128 + (rl ^ ((cl & 7) << 3))] = f2h(v);
            }
        }
    }
    __syncthreads();
    if (wsel < 2) {
        short* outp = wsel ? kfp : qfp;
#pragma unroll
        for (int it = 0; it < 8; it++) {
            const int u = it * 256 + tid;
            const int r = u >> 4, c8 = (u & 15) * 8;
            const s16x8 val = *(const s16x8*)&cbuf[r * 128 + (c8 ^ ((r & 7) << 3))];
            *(s16x8*)&outp[(size_t)(bm + r) * DD + bnl + c8] = val;
        }
    } else {
        const int b = bm >> 11, s0 = bm & 2047;
#pragma unroll
        for (int it = 0; it < 8; it++) {
            const int idx = it * 256 + tid;
            const int dd = idx >> 4, c8 = (idx & 15) * 8;
            const s16x8 val = *(const s16x8*)&cbuf[dd * 128 + (c8 ^ ((dd & 7) << 3))];
            *(s16x8*)&vt[((size_t)b << 20) + ((size_t)(bnl + dd) << 11) + s0 + c8] = val;
        }
    }
}

// ---------------------------------------------------------------------------
// PV fused: combines rowstats (8 partials/row) then computes P inline.
// A-tiles: reg-load raw int16 scores (coalesced) -> exp*inv -> fp16
// ds_write to swizzled LDS. B (Vt) stays on the gload_lds path.
// Structure otherwise identical to R13 pv (BK=64 dbuf, 16 MFMA/barrier).
// ---------------------------------------------------------------------------
__global__ __launch_bounds__(256, 3) void pv_fused(
    const short* __restrict__ S, const short* __restrict__ vt,
    const float2* __restrict__ rowstat, float* __restrict__ out, int nwg)
{
    __shared__ short As[2][64 * 64];
    __shared__ short Bs[2][128 * 64];
    __shared__ float mrowL[64], sinvL[64];

    const int tid = threadIdx.x;
    const int wave = tid >> 6, lane = tid & 63;
    const int flat = blockIdx.x + 4 * blockIdx.y + 128 * blockIdx.z;
    const int w = (flat & 7) * (nwg >> 3) + (flat >> 3);
    const int bm = ((w >> 2) & 31) * 64, bn = (w & 3) * 128;
    const long z = w >> 7;
    S += z * (long)SS * SS;
    vt += z << 20;
    out += z * (long)SS * DD;
    rowstat += z * 8 * SS;

    // combine per-block stats -> row max, inv sumexp
    if (tid < 64) {
        float2 v[8];
        float m = -3e38f;
#pragma unroll
        for (int b = 0; b < 8; b++) {
            v[b] = rowstat[(size_t)b * SS + bm + tid];
            m = fmaxf(m, v[b].x);
        }
        float s = 0.f;
#pragma unroll
        for (int b = 0; b < 8; b++) s += v[b].y * __expf(v[b].x - m);
        mrowL[tid] = m;
        sinvL[tid] = 1.0f / s;
    }
    __syncthreads();

    const int ar0 = tid >> 3, ac0 = (tid & 7) * 8;
    const float m0 = mrowL[ar0], i0 = sinvL[ar0];
    const float m1 = mrowL[32 + ar0], i1 = sinvL[32 + ar0];

    f32x4 acc[2][4] = {};
    const int wm = (wave >> 1) * 32, wn = (wave & 1) * 64;
    const int lrow = lane & 15, lk = (lane >> 4) * 8;

    auto swz = [](int L) { return L ^ (((L >> 7) & 7) << 4); };
    auto issueB = [&](int buf, int k0) {
#pragma unroll
        for (int h = 0; h < 4; h++) {
            const int L = (h << 12) + (tid << 4);
            const int Ls = swz(L);
            const int row = Ls >> 7, col = (Ls & 127) >> 1;
            gload_lds16(vt + ((size_t)(bn + row) << 11) + k0 + col, (char*)&Bs[buf][0] + L);
        }
    };
    auto loadA = [&](int k0, s16x8& r0, s16x8& r1) {
        r0 = *(const s16x8*)&S[(size_t)(bm + ar0) * SS + k0 + ac0];
        r1 = *(const s16x8*)&S[(size_t)(bm + 32 + ar0) * SS + k0 + ac0];
    };
    auto expWrite = [&](int buf, s16x8 r, int rowbase, float mm, float ii) {
        s16x8 o;
#pragma unroll
        for (int j = 0; j < 8; j++)
            o[j] = f2h(__expf((float)(int)r[j] * 0.0078125f - mm) * ii);
        const int L = ((rowbase + ar0) << 7) + ((tid & 7) << 4);
        *(s16x8*)((char*)&As[buf][0] + swz(L)) = o;
    };

#define PV_TILE(T, CUR, PREF)                                                    \
  {                                                                              \
    s16x8 a[2][2], b[2][4];                                                      \
    _Pragma("unroll")                                                            \
    for (int kx = 0; kx < 2; kx++) {                                             \
      _Pragma("unroll")                                                          \
      for (int m = 0; m < 2; m++)                                                \
        a[kx][m] = *(const s16x8*)((const char*)&As[CUR][0] +                    \
                   swz(((wm + m * 16 + lrow) * 64 + kx * 32 + lk) * 2));         \
      _Pragma("unroll")                                                          \
      for (int n = 0; n < 4; n++)                                                \
        b[kx][n] = *(const s16x8*)((const char*)&Bs[CUR][0] +                    \
                   swz(((wn + n * 16 + lrow) * 64 + kx * 32 + lk) * 2));         \
    }                                                                            \
    s16x8 n0, n1;                                                                \
    if (PREF) { issueB((CUR) ^ 1, ((T) + 1) * 64); SB0;                          \
                loadA(((T) + 1) * 64, n0, n1); }                                 \
    LGKM0; SB0;                                                                  \
    __builtin_amdgcn_s_setprio(1);                                               \
    _Pragma("unroll")                                                            \
    for (int kx = 0; kx < 2; kx++) {                                             \
      _Pragma("unroll")                                                          \
      for (int m = 0; m < 2; m++) {                                              \
        _Pragma("unroll")                                                        \
        for (int n = 0; n < 4; n++)                                              \
          acc[m][n] = __builtin_amdgcn_mfma_f32_16x16x32_f16(                    \
              as_h(a[kx][m]), as_h(b[kx][n]), acc[m][n], 0, 0, 0);               \
      }                                                                          \
    }                                                                            \
    __builtin_amdgcn_s_setprio(0);                                               \
    if (PREF) {                                                                  \
      VM0; SB0;                                                                  \
      expWrite((CUR) ^ 1, n0, 0, m0, i0);                                        \
      expWrite((CUR) ^ 1, n1, 32, m1, i1);                                       \
      LGKM0; SB0;                                                                \
    }                                                                            \
    __builtin_amdgcn_s_barrier();                                                \
  }

    // prologue: stage tile 0
    issueB(0, 0);
    {
        s16x8 p0, p1;
        loadA(0, p0, p1);
        VM0;
        expWrite(0, p0, 0, m0, i0);
        expWrite(0, p1, 32, m1, i1);
        LGKM0;
    }
    __builtin_amdgcn_s_barrier();

    for (int t = 0; t < 32; t += 2) {
        PV_TILE(t,     0, 1);
        PV_TILE(t + 1, 1, (t + 1) < 31);
    }
#undef PV_TILE

#pragma unroll
    for (int m = 0; m < 2; m++) {
#pragma unroll
        for (int n = 0; n < 4; n++) {
#pragma unroll
            for (int j = 0; j < 4; j++) {
                const int row = bm + wm + m * 16 + (lane >> 4) * 4 + j;
                const int col = bn + wn + n * 16 + lrow;
                out[(size_t)row * DD + col] = acc[m][n][j];
            }
        }
    }
}

// merged casts (R9-proven, unchanged)
__global__ __launch_bounds__(256) void cast_all(
    const float* __restrict__ x,
    const float* __restrict__ wq, const float* __restrict__ wk,
    const float* __restrict__ wv,
    short* __restrict__ xh, short* __restrict__ xl,
    short* __restrict__ wt)
{
    const int bid = blockIdx.x;
    if (bid < 4096) {
        const int i = bid * 256 + threadIdx.x;
        const float4 v = ((const float4*)x)[i];
        const float vv[4] = {v.x, v.y, v.z, v.w};
        s16x4 h, l;
#pragma unroll
        for (int j = 0; j < 4; j++) {
            const short hh = f2h(vv[j]);
            h[j] = hh;
            l[j] = f2h(vv[j] - h2f(hh));
        }
        ((s16x4*)xh)[i] = h;
        ((s16x4*)xl)[i] = l;
    } else {
        const int t = (bid - 4096) * 256 + threadIdx.x;
        const int w = t >> 18;
        const int r = t & 262143;
        const float* src = (w == 0) ? wq : ((w == 1) ? wk : wv);
        const float v = src[r];
        const int k = r >> 9, n = r & 511;
        wt[((size_t)w << 18) + ((size_t)n << 9) + k] = f2h(v);
    }
}

extern "C" void kernel_launch(void* const* d_in, const int* in_sizes, int n_in,
                              void* d_out, int out_size, void* d_ws, size_t ws_size,
                              hipStream_t stream)
{
    const float* x  = (const float*)d_in[0];
    const float* Wq = (const float*)d_in[1];
    const float* Wk = (const float*)d_in[2];
    const float* Wv = (const float*)d_in[3];
    const float* bq = (const float*)d_in[4];
    const float* bk = (const float*)d_in[5];
    const float* bv = (const float*)d_in[6];
    float* out = (float*)d_out;

    const size_t MK = (size_t)BB * SS * DD;
    char* ws = (char*)d_ws;
    short* xh  = (short*)ws; ws += MK * 2;
    short* xl  = (short*)ws; ws += MK * 2;
    short* wt  = (short*)ws; ws += 3ull * DD * DD * 2;
    short* qfp = (short*)ws; ws += MK * 2;
    short* kfp = (short*)ws; ws += MK * 2;
    short* vt  = (short*)ws; ws += MK * 2;
    float2* rowstat = (float2*)ws; ws += (size_t)BB * 8 * SS * sizeof(float2);
    const size_t fixed = (size_t)(ws - (char*)d_ws);

    int g = 4;
    while (g > 0 && fixed + (size_t)g * ((size_t)SS * SS * 2) > ws_size)
        g >>= 1;
    if (g == 0) return;
    short* sc = (short*)ws;

    cast_all<<<dim3(7168), 256, 0, stream>>>(x, Wq, Wk, Wv, xh, xl, wt);
    proj_all<<<dim3(12, 64), 256, 0, stream>>>(xh, xl, wt, bq, bk, bv,
                                               qfp, kfp, vt);

    for (int b0 = 0; b0 < BB; b0 += g) {
        const int gg = (b0 + g <= BB) ? g : (BB - b0);
        qkt256<<<dim3(8, 8, gg), 512, 0, stream>>>(
            qfp + (size_t)b0 * SS * DD, kfp + (size_t)b0 * SS * DD,
            sc, rowstat + (size_t)b0 * 8 * SS, 64 * gg);
        pv_fused<<<dim3(4, 32, gg), 256, 0, stream>>>(
            sc, vt + ((size_t)b0 << 20),
            rowstat + (size_t)b0 * 8 * SS, out + (size_t)b0 * SS * DD, 128 * gg);
    }
}

// Round 15
// 109.153 us; speedup vs baseline: 1.0225x; 1.0225x over previous
//
#include <hip/hip_runtime.h>
#include <hip/hip_bf16.h>
#include <hip/hip_fp16.h>

#define BB 4
#define SS 2048
#define DD 512

typedef short s16x8 __attribute__((ext_vector_type(8)));
typedef short s16x4 __attribute__((ext_vector_type(4)));
typedef float f32x4 __attribute__((ext_vector_type(4)));
typedef _Float16 f16x8 __attribute__((ext_vector_type(8)));

__device__ __forceinline__ short f2h(float f) {
    const _Float16 h = (_Float16)f;
    union { _Float16 h; short s; } u; u.h = h; return u.s;
}
__device__ __forceinline__ float h2f(short s) {
    union { short s; _Float16 h; } u; u.s = s; return (float)u.h;
}
__device__ __forceinline__ f16x8 as_h(s16x8 v) {
    union { s16x8 s; f16x8 h; } u; u.s = v; return u.h;
}

__device__ __forceinline__ void gload_lds16(const void* g, void* l) {
    __builtin_amdgcn_global_load_lds(
        (const __attribute__((address_space(1))) void*)g,
        (__attribute__((address_space(3))) void*)l, 16, 0, 0);
}

#define SB0 __builtin_amdgcn_sched_barrier(0)
#define LGKM0 asm volatile("s_waitcnt lgkmcnt(0)" ::: "memory")
#define VM0   asm volatile("s_waitcnt vmcnt(0)" ::: "memory")

// ---------------------------------------------------------------------------
// QK^T 256x256, BK=32, 8 waves, fp16, XCD swizzle, single-phase-per-tile
// (R12-proven loop). LDS cut 128->64 KiB (2 blocks/CU: m114 cross-block
// drain hiding). int16 scores via TWO half-repack passes (64 KiB ebuf).
// ---------------------------------------------------------------------------
__global__ __launch_bounds__(512, 2) void qkt256(
    const short* __restrict__ qf, const short* __restrict__ kf,
    short* __restrict__ outS, int nwg)
{
    __shared__ short lds[32768];  // 64 KiB: [2 buf][2 arr][8192]; ebuf reuse

    const int tid = threadIdx.x;
    const int wave = tid >> 6, lane = tid & 63;
    const int flat = blockIdx.x + 8 * blockIdx.y + 64 * blockIdx.z;
    const int w = (flat & 7) * (nwg >> 3) + (flat >> 3);
    const int bm = ((w >> 3) & 7) * 256, bn = (w & 7) * 256;
    const long z = w >> 6;
    qf += z * (long)SS * DD; kf += z * (long)SS * DD;
    outS += z * (long)SS * SS;

    const int wm = (wave >> 2) * 128, wn = (wave & 3) * 64;
    const int lrow = lane & 15, lk16 = (lane >> 4) * 16;

    f32x4 acc[8][4] = {};

    auto base = [&](int buf, int arr) -> short* { return &lds[(buf * 2 + arr) * 8192]; };
    auto issue = [&](int buf, int arr, int k0) {
#pragma unroll
        for (int h = 0; h < 2; h++) {
            const int Lb = (h << 13) + (tid << 4);
            const int Ls = Lb ^ (((Lb >> 7) & 3) << 4);
            const int row = Ls >> 6, elem = (Ls & 63) >> 1;
            const short* s = arr ? kf : qf;
            const int rb = arr ? bn : bm;
            gload_lds16(s + (size_t)(rb + row) * DD + k0 + elem,
                        (char*)base(buf, arr) + Lb);
        }
    };
    auto rd = [&](int buf, int arr, int row) -> s16x8 {
        const int L = (row << 6) + lk16;
        const int Ls = L ^ (((L >> 7) & 3) << 4);
        return *(const s16x8*)((const char*)base(buf, arr) + Ls);
    };

#define QK_TILE(T, CUR, PREF)                                                    \
  {                                                                              \
    s16x8 a[8], b[4];                                                            \
    _Pragma("unroll")                                                            \
    for (int m = 0; m < 8; m++) a[m] = rd(CUR, 0, wm + m * 16 + lrow);           \
    _Pragma("unroll")                                                            \
    for (int n = 0; n < 4; n++) b[n] = rd(CUR, 1, wn + n * 16 + lrow);           \
    if (PREF) { issue((CUR) ^ 1, 1, ((T) + 1) * 32); SB0;                        \
                issue((CUR) ^ 1, 0, ((T) + 1) * 32); }                           \
    LGKM0; SB0;                                                                  \
    __builtin_amdgcn_s_setprio(1);                                               \
    _Pragma("unroll")                                                            \
    for (int m = 0; m < 8; m++) {                                                \
      _Pragma("unroll")                                                          \
      for (int n = 0; n < 4; n++)                                                \
        acc[m][n] = __builtin_amdgcn_mfma_f32_16x16x32_f16(                      \
            as_h(a[m]), as_h(b[n]), acc[m][n], 0, 0, 0);                         \
    }                                                                            \
    __builtin_amdgcn_s_setprio(0);                                               \
    if (PREF) { VM0; SB0; }                                                      \
    __builtin_amdgcn_s_barrier();                                                \
  }

    issue(0, 1, 0); issue(0, 0, 0);
    VM0;
    __builtin_amdgcn_s_barrier();

    for (int t = 0; t < 16; t += 2) {
        QK_TILE(t,     0, 1);
        QK_TILE(t + 1, 1, (t + 1) < 15);
    }
#undef QK_TILE

    // epilogue: two half-repacks through 64 KiB ebuf ([128][256] int16).
    short* ebuf = &lds[0];
#pragma unroll
    for (int half = 0; half < 2; half++) {
        __syncthreads();
        if ((wave >> 2) == half) {  // waves whose wm matches this half
#pragma unroll
            for (int m = 0; m < 8; m++) {
#pragma unroll
                for (int n = 0; n < 4; n++) {
#pragma unroll
                    for (int j = 0; j < 4; j++) {
                        const int rl = m * 16 + (lane >> 4) * 4 + j;  // 0..127
                        const int cl = wn + n * 16 + lrow;
                        const int pcb = (cl >> 3) ^ ((rl & 3) << 1);
                        ebuf[rl * 256 + pcb * 8 + (cl & 7)] =
                            (short)__float2int_rn(acc[m][n][j] * 128.0f);
                    }
                }
            }
        }
        __syncthreads();
#pragma unroll
        for (int it = 0; it < 8; it++) {
            const int u = it * 512 + tid;
            const int R = u >> 5, cb = u & 31;
            const int pcb = cb ^ ((R & 3) << 1);
            const s16x8 val = *(const s16x8*)&ebuf[R * 256 + pcb * 8];
            *(s16x8*)&outS[(size_t)(bm + half * 128 + R) * SS + bn + cb * 8] = val;
        }
    }
}

// ---------------------------------------------------------------------------
// Unified projection, all-fp16, single-phase-per-tile + chunked XCD swizzle
// (R13-proven, unchanged).
// ---------------------------------------------------------------------------
__global__ __launch_bounds__(256, 3) void proj_all(
    const short* __restrict__ xh, const short* __restrict__ xl,
    const short* __restrict__ wt,
    const float* __restrict__ bq, const float* __restrict__ bk,
    const float* __restrict__ bv,
    short* __restrict__ qfp, short* __restrict__ kfp, short* __restrict__ vt)
{
    __shared__ short lds[24576];

    const int tid = threadIdx.x;
    const int wave = tid >> 6, lane = tid & 63;
    const int flat = blockIdx.x + 12 * blockIdx.y;
    const int w = (flat & 7) * 96 + (flat >> 3);
    const int bxi = w % 12, byi = w / 12;
    const int wsel = bxi >> 2;
    const int bnl = (bxi & 3) * 128;
    const int bm = byi * 128;
    const bool lo = (wsel < 2);
    const short* B0 = wt + (size_t)wsel * DD * DD;
    const float* bias = (wsel == 0) ? bq : (wsel == 1) ? bk : bv;

    f32x4 acc[4][4] = {};
    const int wm = (wave >> 1) * 64, wn = (wave & 1) * 64;
    const int lrow = lane & 15, lk16 = (lane >> 4) * 16;

    auto base = [&](int buf, int arr) -> short* { return &lds[(buf * 3 + arr) * 4096]; };
    auto issue = [&](int buf, int arr, int k0) {
#pragma unroll
        for (int h = 0; h < 2; h++) {
            const int Lb = (h << 12) + (tid << 4);
            const int Ls = Lb ^ (((Lb >> 7) & 3) << 4);
            const int row = Ls >> 6, elem = (Ls & 63) >> 1;
            const short* s = (arr == 0) ? xh : (arr == 1) ? xl : B0;
            const int rb = (arr < 2) ? bm : bnl;
            gload_lds16(s + (size_t)(rb + row) * DD + k0 + elem,
                        (char*)base(buf, arr) + Lb);
        }
    };
    auto rd = [&](int buf, int arr, int row) -> s16x8 {
        const int L = (row << 6) + lk16;
        const int Ls = L ^ (((L >> 7) & 3) << 4);
        return *(const s16x8*)((const char*)base(buf, arr) + Ls);
    };

#define PJ_TILE(T, CUR, PREF)                                                    \
  {                                                                              \
    s16x8 ah[4], al[4], b[4];                                                    \
    _Pragma("unroll")                                                            \
    for (int m = 0; m < 4; m++) ah[m] = rd(CUR, 0, wm + m * 16 + lrow);          \
    if (lo) {                                                                    \
      _Pragma("unroll")                                                          \
      for (int m = 0; m < 4; m++) al[m] = rd(CUR, 1, wm + m * 16 + lrow);        \
    }                                                                            \
    _Pragma("unroll")                                                            \
    for (int n = 0; n < 4; n++) b[n] = rd(CUR, 2, wn + n * 16 + lrow);           \
    if (PREF) {                                                                  \
      issue((CUR) ^ 1, 2, ((T) + 1) * 32); SB0;                                  \
      issue((CUR) ^ 1, 0, ((T) + 1) * 32);                                       \
      if (lo) issue((CUR) ^ 1, 1, ((T) + 1) * 32);                               \
    }                                                                            \
    LGKM0; SB0;                                                                  \
    __builtin_amdgcn_s_setprio(1);                                               \
    _Pragma("unroll")                                                            \
    for (int m = 0; m < 4; m++) {                                                \
      _Pragma("unroll")                                                          \
      for (int n = 0; n < 4; n++) {                                              \
        acc[m][n] = __builtin_amdgcn_mfma_f32_16x16x32_f16(                      \
            as_h(ah[m]), as_h(b[n]), acc[m][n], 0, 0, 0);                        \
        if (lo)                                                                  \
          acc[m][n] = __builtin_amdgcn_mfma_f32_16x16x32_f16(                    \
              as_h(al[m]), as_h(b[n]), acc[m][n], 0, 0, 0);                      \
      }                                                                          \
    }                                                                            \
    __builtin_amdgcn_s_setprio(0);                                               \
    if (PREF) { VM0; SB0; }                                                      \
    __builtin_amdgcn_s_barrier();                                                \
  }

    issue(0, 2, 0); issue(0, 0, 0);
    if (lo) issue(0, 1, 0);
    VM0;
    __builtin_amdgcn_s_barrier();

    for (int t = 0; t < 16; t += 2) {
        PJ_TILE(t,     0, 1);
        PJ_TILE(t + 1, 1, (t + 1) < 15);
    }
#undef PJ_TILE

    __syncthreads();
    short* cbuf = &lds[0];
#pragma unroll
    for (int m = 0; m < 4; m++) {
#pragma unroll
        for (int n = 0; n < 4; n++) {
#pragma unroll
            for (int j = 0; j < 4; j++) {
                const int rl = wm + m * 16 + (lane >> 4) * 4 + j;
                const int cl = wn + n * 16 + lrow;
                const float v = acc[m][n][j] + bias[bnl + cl];
                if (wsel < 2)
                    cbuf[rl * 128 + (cl ^ ((rl & 7) << 3))] = f2h(v);
                else
                    cbuf[cl * 128 + (rl ^ ((cl & 7) << 3))] = f2h(v);
            }
        }
    }
    __syncthreads();
    if (wsel < 2) {
        short* outp = wsel ? kfp : qfp;
#pragma unroll
        for (int it = 0; it < 8; it++) {
            const int u = it * 256 + tid;
            const int r = u >> 4, c8 = (u & 15) * 8;
            const s16x8 val = *(const s16x8*)&cbuf[r * 128 + (c8 ^ ((r & 7) << 3))];
            *(s16x8*)&outp[(size_t)(bm + r) * DD + bnl + c8] = val;
        }
    } else {
        const int b = bm >> 11, s0 = bm & 2047;
#pragma unroll
        for (int it = 0; it < 8; it++) {
            const int idx = it * 256 + tid;
            const int dd = idx >> 4, c8 = (idx & 15) * 8;
            const s16x8 val = *(const s16x8*)&cbuf[dd * 128 + (c8 ^ ((dd & 7) << 3))];
            *(s16x8*)&vt[((size_t)b << 20) + ((size_t)(bnl + dd) << 11) + s0 + c8] = val;
        }
    }
}

// ---------------------------------------------------------------------------
// PV GEMM fp16: 64x128 tile, BK=64 dbuf, single-phase-per-tile + chunked
// XCD swizzle (R13-proven, unchanged).
// ---------------------------------------------------------------------------
__global__ __launch_bounds__(256, 3) void pv_gemm(
    const short* __restrict__ P, const short* __restrict__ vt,
    float* __restrict__ out, int nwg)
{
    __shared__ short As[2][64 * 64];
    __shared__ short Bs[2][128 * 64];

    const int tid = threadIdx.x;
    const int wave = tid >> 6, lane = tid & 63;
    const int flat = blockIdx.x + 4 * blockIdx.y + 128 * blockIdx.z;
    const int w = (flat & 7) * (nwg >> 3) + (flat >> 3);
    const int bm = ((w >> 2) & 31) * 64, bn = (w & 3) * 128;
    const long z = w >> 7;
    P += z * (long)SS * SS;
    vt += z << 20;
    out += z * (long)SS * DD;

    f32x4 acc[2][4] = {};
    const int wm = (wave >> 1) * 32, wn = (wave & 1) * 64;
    const int lrow = lane & 15, lk = (lane >> 4) * 8;

    auto swz = [](int L) { return L ^ (((L >> 7) & 7) << 4); };
    auto issueA = [&](int buf, int k0) {
#pragma unroll
        for (int h = 0; h < 2; h++) {
            const int L = (h << 12) + (tid << 4);
            const int Ls = swz(L);
            const int row = Ls >> 7, col = (Ls & 127) >> 1;
            gload_lds16(P + (size_t)(bm + row) * SS + k0 + col, (char*)&As[buf][0] + L);
        }
    };
    auto issueB = [&](int buf, int k0) {
#pragma unroll
        for (int h = 0; h < 4; h++) {
            const int L = (h << 12) + (tid << 4);
            const int Ls = swz(L);
            const int row = Ls >> 7, col = (Ls & 127) >> 1;
            gload_lds16(vt + ((size_t)(bn + row) << 11) + k0 + col, (char*)&Bs[buf][0] + L);
        }
    };

#define PV_TILE(T, CUR, PREF)                                                    \
  {                                                                              \
    s16x8 a[2][2], b[2][4];                                                      \
    _Pragma("unroll")                                                            \
    for (int kx = 0; kx < 2; kx++) {                                             \
      _Pragma("unroll")                                                          \
      for (int m = 0; m < 2; m++)                                                \
        a[kx][m] = *(const s16x8*)((const char*)&As[CUR][0] +                    \
                   swz(((wm + m * 16 + lrow) * 64 + kx * 32 + lk) * 2));         \
      _Pragma("unroll")                                                          \
      for (int n = 0; n < 4; n++)                                                \
        b[kx][n] = *(const s16x8*)((const char*)&Bs[CUR][0] +                    \
                   swz(((wn + n * 16 + lrow) * 64 + kx * 32 + lk) * 2));         \
    }                                                                            \
    if (PREF) { issueB((CUR) ^ 1, ((T) + 1) * 64); SB0;                          \
                issueA((CUR) ^ 1, ((T) + 1) * 64); }                             \
    LGKM0; SB0;                                                                  \
    __builtin_amdgcn_s_setprio(1);                                               \
    _Pragma("unroll")                                                            \
    for (int kx = 0; kx < 2; kx++) {                                             \
      _Pragma("unroll")                                                          \
      for (int m = 0; m < 2; m++) {                                              \
        _Pragma("unroll")                                                        \
        for (int n = 0; n < 4; n++)                                              \
          acc[m][n] = __builtin_amdgcn_mfma_f32_16x16x32_f16(                    \
              as_h(a[kx][m]), as_h(b[kx][n]), acc[m][n], 0, 0, 0);               \
      }                                                                          \
    }                                                                            \
    __builtin_amdgcn_s_setprio(0);                                               \
    if (PREF) { VM0; SB0; }                                                      \
    __builtin_amdgcn_s_barrier();                                                \
  }

    issueB(0, 0); issueA(0, 0);
    VM0;
    __builtin_amdgcn_s_barrier();

    for (int t = 0; t < 32; t += 2) {
        PV_TILE(t,     0, 1);
        PV_TILE(t + 1, 1, (t + 1) < 31);
    }
#undef PV_TILE

#pragma unroll
    for (int m = 0; m < 2; m++) {
#pragma unroll
        for (int n = 0; n < 4; n++) {
#pragma unroll
            for (int j = 0; j < 4; j++) {
                const int row = bm + wm + m * 16 + (lane >> 4) * 4 + j;
                const int col = bn + wn + n * 16 + lrow;
                out[(size_t)row * DD + col] = acc[m][n][j];
            }
        }
    }
}

// merged casts (R9-proven, unchanged)
__global__ __launch_bounds__(256) void cast_all(
    const float* __restrict__ x,
    const float* __restrict__ wq, const float* __restrict__ wk,
    const float* __restrict__ wv,
    short* __restrict__ xh, short* __restrict__ xl,
    short* __restrict__ wt)
{
    const int bid = blockIdx.x;
    if (bid < 4096) {
        const int i = bid * 256 + threadIdx.x;
        const float4 v = ((const float4*)x)[i];
        const float vv[4] = {v.x, v.y, v.z, v.w};
        s16x4 h, l;
#pragma unroll
        for (int j = 0; j < 4; j++) {
            const short hh = f2h(vv[j]);
            h[j] = hh;
            l[j] = f2h(vv[j] - h2f(hh));
        }
        ((s16x4*)xh)[i] = h;
        ((s16x4*)xl)[i] = l;
    } else {
        const int t = (bid - 4096) * 256 + threadIdx.x;
        const int w = t >> 18;
        const int r = t & 262143;
        const float* src = (w == 0) ? wq : ((w == 1) ? wk : wv);
        const float v = src[r];
        const int k = r >> 9, n = r & 511;
        wt[((size_t)w << 18) + ((size_t)n << 9) + k] = f2h(v);
    }
}

// softmax over int16 scores (scale 1/128), fp16 P out (R10-proven, unchanged)
__global__ __launch_bounds__(256) void softmax_rows(
    const short* __restrict__ S, short* __restrict__ P)
{
    const int row = blockIdx.x;
    const long z = blockIdx.y;
    const short* s = S + z * (long)SS * SS + (long)row * SS;
    short* p = P + z * (long)SS * SS + (long)row * SS;
    const int tid = threadIdx.x;

    const s16x8 raw = ((const s16x8*)s)[tid];
    float v[8];
#pragma unroll
    for (int j = 0; j < 8; j++) v[j] = (float)(int)raw[j] * 0.0078125f;

    float m = v[0];
#pragma unroll
    for (int j = 1; j < 8; j++) m = fmaxf(m, v[j]);
#pragma unroll
    for (int off = 32; off >= 1; off >>= 1) m = fmaxf(m, __shfl_xor(m, off));
    __shared__ float redm[4], reds[4];
    if ((tid & 63) == 0) redm[tid >> 6] = m;
    __syncthreads();
    m = fmaxf(fmaxf(redm[0], redm[1]), fmaxf(redm[2], redm[3]));

    float e[8], sum = 0.f;
#pragma unroll
    for (int j = 0; j < 8; j++) { e[j] = __expf(v[j] - m); sum += e[j]; }
#pragma unroll
    for (int off = 32; off >= 1; off >>= 1) sum += __shfl_xor(sum, off);
    if ((tid & 63) == 0) reds[tid >> 6] = sum;
    __syncthreads();
    sum = reds[0] + reds[1] + reds[2] + reds[3];
    const float inv = 1.0f / sum;

    s16x8 o;
#pragma unroll
    for (int j = 0; j < 8; j++) o[j] = f2h(e[j] * inv);
    ((s16x8*)p)[tid] = o;
}

extern "C" void kernel_launch(void* const* d_in, const int* in_sizes, int n_in,
                              void* d_out, int out_size, void* d_ws, size_t ws_size,
                              hipStream_t stream)
{
    const float* x  = (const float*)d_in[0];
    const float* Wq = (const float*)d_in[1];
    const float* Wk = (const float*)d_in[2];
    const float* Wv = (const float*)d_in[3];
    const float* bq = (const float*)d_in[4];
    const float* bk = (const float*)d_in[5];
    const float* bv = (const float*)d_in[6];
    float* out = (float*)d_out;

    const size_t MK = (size_t)BB * SS * DD;
    char* ws = (char*)d_ws;
    short* xh  = (short*)ws; ws += MK * 2;
    short* xl  = (short*)ws; ws += MK * 2;
    short* wt  = (short*)ws; ws += 3ull * DD * DD * 2;
    short* qfp = (short*)ws; ws += MK * 2;
    short* kfp = (short*)ws; ws += MK * 2;
    short* vt  = (short*)ws; ws += MK * 2;
    const size_t fixed = (size_t)(ws - (char*)d_ws);

    int g = 4;
    while (g > 0 && fixed + (size_t)g * ((size_t)SS * SS * 2 + (size_t)SS * SS * 2) > ws_size)
        g >>= 1;
    if (g == 0) return;
    short* sc = (short*)ws;
    short* P  = (short*)(ws + (size_t)g * SS * SS * 2);

    cast_all<<<dim3(7168), 256, 0, stream>>>(x, Wq, Wk, Wv, xh, xl, wt);
    proj_all<<<dim3(12, 64), 256, 0, stream>>>(xh, xl, wt, bq, bk, bv,
                                               qfp, kfp, vt);

    for (int b0 = 0; b0 < BB; b0 += g) {
        const int gg = (b0 + g <= BB) ? g : (BB - b0);
        qkt256<<<dim3(8, 8, gg), 512, 0, stream>>>(
            qfp + (size_t)b0 * SS * DD, kfp + (size_t)b0 * SS * DD, sc, 64 * gg);
        softmax_rows<<<dim3(SS, gg), 256, 0, stream>>>(sc, P);
        pv_gemm<<<dim3(4, 32, gg), 256, 0, stream>>>(
            P, vt + ((size_t)b0 << 20), out + (size_t)b0 * SS * DD, 128 * gg);
    }
}

// Round 16
// 108.121 us; speedup vs baseline: 1.0323x; 1.0095x over previous
//
#include <hip/hip_runtime.h>
#include <hip/hip_bf16.h>
#include <hip/hip_fp16.h>

#define BB 4
#define SS 2048
#define DD 512

typedef short s16x8 __attribute__((ext_vector_type(8)));
typedef short s16x4 __attribute__((ext_vector_type(4)));
typedef float f32x4 __attribute__((ext_vector_type(4)));
typedef _Float16 f16x8 __attribute__((ext_vector_type(8)));

__device__ __forceinline__ short f2h(float f) {
    const _Float16 h = (_Float16)f;
    union { _Float16 h; short s; } u; u.h = h; return u.s;
}
__device__ __forceinline__ float h2f(short s) {
    union { short s; _Float16 h; } u; u.s = s; return (float)u.h;
}
__device__ __forceinline__ f16x8 as_h(s16x8 v) {
    union { s16x8 s; f16x8 h; } u; u.s = v; return u.h;
}

__device__ __forceinline__ void gload_lds16(const void* g, void* l) {
    __builtin_amdgcn_global_load_lds(
        (const __attribute__((address_space(1))) void*)g,
        (__attribute__((address_space(3))) void*)l, 16, 0, 0);
}

#define SB0 __builtin_amdgcn_sched_barrier(0)
#define LGKM0 asm volatile("s_waitcnt lgkmcnt(0)" ::: "memory")
#define VM0   asm volatile("s_waitcnt vmcnt(0)" ::: "memory")

// ---------------------------------------------------------------------------
// QK^T 128x128 tile, BK=32, 4 waves (proj_all's proven shape: 256 thr,
// 32 KiB LDS -> 4 blocks/CU co-residency hides the per-tile drain, m114).
// fp16 single-pass, chunked XCD swizzle (per-XCD 8 q + 16 k panels = 3 MB).
// int16 scores (scale 128) via proj-style cbuf repack -> coalesced stores.
// ---------------------------------------------------------------------------
__global__ __launch_bounds__(256, 4) void qkt128(
    const short* __restrict__ qf, const short* __restrict__ kf,
    short* __restrict__ outS, int nwg)
{
    __shared__ short lds[16384];  // [2 buf][2 arr][4096] = 32 KiB; ebuf reuse

    const int tid = threadIdx.x;
    const int wave = tid >> 6, lane = tid & 63;
    const int flat = blockIdx.x + 16 * blockIdx.y + 256 * blockIdx.z;
    const int w = (flat & 7) * (nwg >> 3) + (flat >> 3);   // chunked XCD map
    const int bm = ((w >> 4) & 15) * 128, bn = (w & 15) * 128;
    const long z = w >> 8;
    qf += z * (long)SS * DD; kf += z * (long)SS * DD;
    outS += z * (long)SS * SS;

    const int wm = (wave >> 1) * 64, wn = (wave & 1) * 64;
    const int lrow = lane & 15, lk16 = (lane >> 4) * 16;

    f32x4 acc[4][4] = {};

    auto base = [&](int buf, int arr) -> short* { return &lds[(buf * 2 + arr) * 4096]; };
    auto issue = [&](int buf, int arr, int k0) {
#pragma unroll
        for (int h = 0; h < 2; h++) {
            const int Lb = (h << 12) + (tid << 4);
            const int Ls = Lb ^ (((Lb >> 7) & 3) << 4);
            const int row = Ls >> 6, elem = (Ls & 63) >> 1;
            const short* s = arr ? kf : qf;
            const int rb = arr ? bn : bm;
            gload_lds16(s + (size_t)(rb + row) * DD + k0 + elem,
                        (char*)base(buf, arr) + Lb);
        }
    };
    auto rd = [&](int buf, int arr, int row) -> s16x8 {
        const int L = (row << 6) + lk16;
        const int Ls = L ^ (((L >> 7) & 3) << 4);
        return *(const s16x8*)((const char*)base(buf, arr) + Ls);
    };

#define QK_TILE(T, CUR, PREF)                                                    \
  {                                                                              \
    s16x8 a[4], b[4];                                                            \
    _Pragma("unroll")                                                            \
    for (int m = 0; m < 4; m++) a[m] = rd(CUR, 0, wm + m * 16 + lrow);           \
    _Pragma("unroll")                                                            \
    for (int n = 0; n < 4; n++) b[n] = rd(CUR, 1, wn + n * 16 + lrow);           \
    if (PREF) { issue((CUR) ^ 1, 1, ((T) + 1) * 32); SB0;                        \
                issue((CUR) ^ 1, 0, ((T) + 1) * 32); }                           \
    LGKM0; SB0;                                                                  \
    __builtin_amdgcn_s_setprio(1);                                               \
    _Pragma("unroll")                                                            \
    for (int m = 0; m < 4; m++) {                                                \
      _Pragma("unroll")                                                          \
      for (int n = 0; n < 4; n++)                                                \
        acc[m][n] = __builtin_amdgcn_mfma_f32_16x16x32_f16(                      \
            as_h(a[m]), as_h(b[n]), acc[m][n], 0, 0, 0);                         \
    }                                                                            \
    __builtin_amdgcn_s_setprio(0);                                               \
    if (PREF) { VM0; SB0; }                                                      \
    __builtin_amdgcn_s_barrier();                                                \
  }

    issue(0, 1, 0); issue(0, 0, 0);
    VM0;
    __builtin_amdgcn_s_barrier();

    for (int t = 0; t < 16; t += 2) {
        QK_TILE(t,     0, 1);
        QK_TILE(t + 1, 1, (t + 1) < 15);
    }
#undef QK_TILE

    // epilogue: proj-style repack (128x128 int16 = 32 KiB) -> coalesced stores
    __syncthreads();
    short* ebuf = &lds[0];
#pragma unroll
    for (int m = 0; m < 4; m++) {
#pragma unroll
        for (int n = 0; n < 4; n++) {
#pragma unroll
            for (int j = 0; j < 4; j++) {
                const int rl = wm + m * 16 + (lane >> 4) * 4 + j;
                const int cl = wn + n * 16 + lrow;
                ebuf[rl * 128 + (cl ^ ((rl & 7) << 3))] =
                    (short)__float2int_rn(acc[m][n][j] * 128.0f);
            }
        }
    }
    __syncthreads();
#pragma unroll
    for (int it = 0; it < 8; it++) {
        const int u = it * 256 + tid;
        const int r = u >> 4, c8 = (u & 15) * 8;
        const s16x8 val = *(const s16x8*)&ebuf[r * 128 + (c8 ^ ((r & 7) << 3))];
        *(s16x8*)&outS[(size_t)(bm + r) * SS + bn + c8] = val;
    }
}

// ---------------------------------------------------------------------------
// Unified projection, all-fp16, single-phase-per-tile + chunked XCD swizzle
// (R13-proven, unchanged).
// ---------------------------------------------------------------------------
__global__ __launch_bounds__(256, 3) void proj_all(
    const short* __restrict__ xh, const short* __restrict__ xl,
    const short* __restrict__ wt,
    const float* __restrict__ bq, const float* __restrict__ bk,
    const float* __restrict__ bv,
    short* __restrict__ qfp, short* __restrict__ kfp, short* __restrict__ vt)
{
    __shared__ short lds[24576];

    const int tid = threadIdx.x;
    const int wave = tid >> 6, lane = tid & 63;
    const int flat = blockIdx.x + 12 * blockIdx.y;
    const int w = (flat & 7) * 96 + (flat >> 3);
    const int bxi = w % 12, byi = w / 12;
    const int wsel = bxi >> 2;
    const int bnl = (bxi & 3) * 128;
    const int bm = byi * 128;
    const bool lo = (wsel < 2);
    const short* B0 = wt + (size_t)wsel * DD * DD;
    const float* bias = (wsel == 0) ? bq : (wsel == 1) ? bk : bv;

    f32x4 acc[4][4] = {};
    const int wm = (wave >> 1) * 64, wn = (wave & 1) * 64;
    const int lrow = lane & 15, lk16 = (lane >> 4) * 16;

    auto base = [&](int buf, int arr) -> short* { return &lds[(buf * 3 + arr) * 4096]; };
    auto issue = [&](int buf, int arr, int k0) {
#pragma unroll
        for (int h = 0; h < 2; h++) {
            const int Lb = (h << 12) + (tid << 4);
            const int Ls = Lb ^ (((Lb >> 7) & 3) << 4);
            const int row = Ls >> 6, elem = (Ls & 63) >> 1;
            const short* s = (arr == 0) ? xh : (arr == 1) ? xl : B0;
            const int rb = (arr < 2) ? bm : bnl;
            gload_lds16(s + (size_t)(rb + row) * DD + k0 + elem,
                        (char*)base(buf, arr) + Lb);
        }
    };
    auto rd = [&](int buf, int arr, int row) -> s16x8 {
        const int L = (row << 6) + lk16;
        const int Ls = L ^ (((L >> 7) & 3) << 4);
        return *(const s16x8*)((const char*)base(buf, arr) + Ls);
    };

#define PJ_TILE(T, CUR, PREF)                                                    \
  {                                                                              \
    s16x8 ah[4], al[4], b[4];                                                    \
    _Pragma("unroll")                                                            \
    for (int m = 0; m < 4; m++) ah[m] = rd(CUR, 0, wm + m * 16 + lrow);          \
    if (lo) {                                                                    \
      _Pragma("unroll")                                                          \
      for (int m = 0; m < 4; m++) al[m] = rd(CUR, 1, wm + m * 16 + lrow);        \
    }                                                                            \
    _Pragma("unroll")                                                            \
    for (int n = 0; n < 4; n++) b[n] = rd(CUR, 2, wn + n * 16 + lrow);           \
    if (PREF) {                                                                  \
      issue((CUR) ^ 1, 2, ((T) + 1) * 32); SB0;                                  \
      issue((CUR) ^ 1, 0, ((T) + 1) * 32);                                       \
      if (lo) issue((CUR) ^ 1, 1, ((T) + 1) * 32);                               \
    }                                                                            \
    LGKM0; SB0;                                                                  \
    __builtin_amdgcn_s_setprio(1);                                               \
    _Pragma("unroll")                                                            \
    for (int m = 0; m < 4; m++) {                                                \
      _Pragma("unroll")                                                          \
      for (int n = 0; n < 4; n++) {                                              \
        acc[m][n] = __builtin_amdgcn_mfma_f32_16x16x32_f16(                      \
            as_h(ah[m]), as_h(b[n]), acc[m][n], 0, 0, 0);                        \
        if (lo)                                                                  \
          acc[m][n] = __builtin_amdgcn_mfma_f32_16x16x32_f16(                    \
              as_h(al[m]), as_h(b[n]), acc[m][n], 0, 0, 0);                      \
      }                                                                          \
    }                                                                            \
    __builtin_amdgcn_s_setprio(0);                                               \
    if (PREF) { VM0; SB0; }                                                      \
    __builtin_amdgcn_s_barrier();                                                \
  }

    issue(0, 2, 0); issue(0, 0, 0);
    if (lo) issue(0, 1, 0);
    VM0;
    __builtin_amdgcn_s_barrier();

    for (int t = 0; t < 16; t += 2) {
        PJ_TILE(t,     0, 1);
        PJ_TILE(t + 1, 1, (t + 1) < 15);
    }
#undef PJ_TILE

    __syncthreads();
    short* cbuf = &lds[0];
#pragma unroll
    for (int m = 0; m < 4; m++) {
#pragma unroll
        for (int n = 0; n < 4; n++) {
#pragma unroll
            for (int j = 0; j < 4; j++) {
                const int rl = wm + m * 16 + (lane >> 4) * 4 + j;
                const int cl = wn + n * 16 + lrow;
                const float v = acc[m][n][j] + bias[bnl + cl];
                if (wsel < 2)
                    cbuf[rl * 128 + (cl ^ ((rl & 7) << 3))] = f2h(v);
                else
                    cbuf[cl * 128 + (rl ^ ((cl & 7) << 3))] = f2h(v);
            }
        }
    }
    __syncthreads();
    if (wsel < 2) {
        short* outp = wsel ? kfp : qfp;
#pragma unroll
        for (int it = 0; it < 8; it++) {
            const int u = it * 256 + tid;
            const int r = u >> 4, c8 = (u & 15) * 8;
            const s16x8 val = *(const s16x8*)&cbuf[r * 128 + (c8 ^ ((r & 7) << 3))];
            *(s16x8*)&outp[(size_t)(bm + r) * DD + bnl + c8] = val;
        }
    } else {
        const int b = bm >> 11, s0 = bm & 2047;
#pragma unroll
        for (int it = 0; it < 8; it++) {
            const int idx = it * 256 + tid;
            const int dd = idx >> 4, c8 = (idx & 15) * 8;
            const s16x8 val = *(const s16x8*)&cbuf[dd * 128 + (c8 ^ ((dd & 7) << 3))];
            *(s16x8*)&vt[((size_t)b << 20) + ((size_t)(bnl + dd) << 11) + s0 + c8] = val;
        }
    }
}

// ---------------------------------------------------------------------------
// PV GEMM fp16: 64x128 tile, BK=64 dbuf, single-phase-per-tile + chunked
// XCD swizzle (R13-proven, unchanged).
// ---------------------------------------------------------------------------
__global__ __launch_bounds__(256, 3) void pv_gemm(
    const short* __restrict__ P, const short* __restrict__ vt,
    float* __restrict__ out, int nwg)
{
    __shared__ short As[2][64 * 64];
    __shared__ short Bs[2][128 * 64];

    const int tid = threadIdx.x;
    const int wave = tid >> 6, lane = tid & 63;
    const int flat = blockIdx.x + 4 * blockIdx.y + 128 * blockIdx.z;
    const int w = (flat & 7) * (nwg >> 3) + (flat >> 3);
    const int bm = ((w >> 2) & 31) * 64, bn = (w & 3) * 128;
    const long z = w >> 7;
    P += z * (long)SS * SS;
    vt += z << 20;
    out += z * (long)SS * DD;

    f32x4 acc[2][4] = {};
    const int wm = (wave >> 1) * 32, wn = (wave & 1) * 64;
    const int lrow = lane & 15, lk = (lane >> 4) * 8;

    auto swz = [](int L) { return L ^ (((L >> 7) & 7) << 4); };
    auto issueA = [&](int buf, int k0) {
#pragma unroll
        for (int h = 0; h < 2; h++) {
            const int L = (h << 12) + (tid << 4);
            const int Ls = swz(L);
            const int row = Ls >> 7, col = (Ls & 127) >> 1;
            gload_lds16(P + (size_t)(bm + row) * SS + k0 + col, (char*)&As[buf][0] + L);
        }
    };
    auto issueB = [&](int buf, int k0) {
#pragma unroll
        for (int h = 0; h < 4; h++) {
            const int L = (h << 12) + (tid << 4);
            const int Ls = swz(L);
            const int row = Ls >> 7, col = (Ls & 127) >> 1;
            gload_lds16(vt + ((size_t)(bn + row) << 11) + k0 + col, (char*)&Bs[buf][0] + L);
        }
    };

#define PV_TILE(T, CUR, PREF)                                                    \
  {                                                                              \
    s16x8 a[2][2], b[2][4];                                                      \
    _Pragma("unroll")                                                            \
    for (int kx = 0; kx < 2; kx++) {                                             \
      _Pragma("unroll")                                                          \
      for (int m = 0; m < 2; m++)                                                \
        a[kx][m] = *(const s16x8*)((const char*)&As[CUR][0] +                    \
                   swz(((wm + m * 16 + lrow) * 64 + kx * 32 + lk) * 2));         \
      _Pragma("unroll")                                                          \
      for (int n = 0; n < 4; n++)                                                \
        b[kx][n] = *(const s16x8*)((const char*)&Bs[CUR][0] +                    \
                   swz(((wn + n * 16 + lrow) * 64 + kx * 32 + lk) * 2));         \
    }                                                                            \
    if (PREF) { issueB((CUR) ^ 1, ((T) + 1) * 64); SB0;                          \
                issueA((CUR) ^ 1, ((T) + 1) * 64); }                             \
    LGKM0; SB0;                                                                  \
    __builtin_amdgcn_s_setprio(1);                                               \
    _Pragma("unroll")                                                            \
    for (int kx = 0; kx < 2; kx++) {                                             \
      _Pragma("unroll")                                                          \
      for (int m = 0; m < 2; m++) {                                              \
        _Pragma("unroll")                                                        \
        for (int n = 0; n < 4; n++)                                              \
          acc[m][n] = __builtin_amdgcn_mfma_f32_16x16x32_f16(                    \
              as_h(a[kx][m]), as_h(b[kx][n]), acc[m][n], 0, 0, 0);               \
      }                                                                          \
    }                                                                            \
    __builtin_amdgcn_s_setprio(0);                                               \
    if (PREF) { VM0; SB0; }                                                      \
    __builtin_amdgcn_s_barrier();                                                \
  }

    issueB(0, 0); issueA(0, 0);
    VM0;
    __builtin_amdgcn_s_barrier();

    for (int t = 0; t < 32; t += 2) {
        PV_TILE(t,     0, 1);
        PV_TILE(t + 1, 1, (t + 1) < 31);
    }
#undef PV_TILE

#pragma unroll
    for (int m = 0; m < 2; m++) {
#pragma unroll
        for (int n = 0; n < 4; n++) {
#pragma unroll
            for (int j = 0; j < 4; j++) {
                const int row = bm + wm + m * 16 + (lane >> 4) * 4 + j;
                const int col = bn + wn + n * 16 + lrow;
                out[(size_t)row * DD + col] = acc[m][n][j];
            }
        }
    }
}

// merged casts (R9-proven, unchanged)
__global__ __launch_bounds__(256) void cast_all(
    const float* __restrict__ x,
    const float* __restrict__ wq, const float* __restrict__ wk,
    const float* __restrict__ wv,
    short* __restrict__ xh, short* __restrict__ xl,
    short* __restrict__ wt)
{
    const int bid = blockIdx.x;
    if (bid < 4096) {
        const int i = bid * 256 + threadIdx.x;
        const float4 v = ((const float4*)x)[i];
        const float vv[4] = {v.x, v.y, v.z, v.w};
        s16x4 h, l;
#pragma unroll
        for (int j = 0; j < 4; j++) {
            const short hh = f2h(vv[j]);
            h[j] = hh;
            l[j] = f2h(vv[j] - h2f(hh));
        }
        ((s16x4*)xh)[i] = h;
        ((s16x4*)xl)[i] = l;
    } else {
        const int t = (bid - 4096) * 256 + threadIdx.x;
        const int w = t >> 18;
        const int r = t & 262143;
        const float* src = (w == 0) ? wq : ((w == 1) ? wk : wv);
        const float v = src[r];
        const int k = r >> 9, n = r & 511;
        wt[((size_t)w << 18) + ((size_t)n << 9) + k] = f2h(v);
    }
}

// softmax over int16 scores (scale 1/128), fp16 P out (R10-proven, unchanged)
__global__ __launch_bounds__(256) void softmax_rows(
    const short* __restrict__ S, short* __restrict__ P)
{
    const int row = blockIdx.x;
    const long z = blockIdx.y;
    const short* s = S + z * (long)SS * SS + (long)row * SS;
    short* p = P + z * (long)SS * SS + (long)row * SS;
    const int tid = threadIdx.x;

    const s16x8 raw = ((const s16x8*)s)[tid];
    float v[8];
#pragma unroll
    for (int j = 0; j < 8; j++) v[j] = (float)(int)raw[j] * 0.0078125f;

    float m = v[0];
#pragma unroll
    for (int j = 1; j < 8; j++) m = fmaxf(m, v[j]);
#pragma unroll
    for (int off = 32; off >= 1; off >>= 1) m = fmaxf(m, __shfl_xor(m, off));
    __shared__ float redm[4], reds[4];
    if ((tid & 63) == 0) redm[tid >> 6] = m;
    __syncthreads();
    m = fmaxf(fmaxf(redm[0], redm[1]), fmaxf(redm[2], redm[3]));

    float e[8], sum = 0.f;
#pragma unroll
    for (int j = 0; j < 8; j++) { e[j] = __expf(v[j] - m); sum += e[j]; }
#pragma unroll
    for (int off = 32; off >= 1; off >>= 1) sum += __shfl_xor(sum, off);
    if ((tid & 63) == 0) reds[tid >> 6] = sum;
    __syncthreads();
    sum = reds[0] + reds[1] + reds[2] + reds[3];
    const float inv = 1.0f / sum;

    s16x8 o;
#pragma unroll
    for (int j = 0; j < 8; j++) o[j] = f2h(e[j] * inv);
    ((s16x8*)p)[tid] = o;
}

extern "C" void kernel_launch(void* const* d_in, const int* in_sizes, int n_in,
                              void* d_out, int out_size, void* d_ws, size_t ws_size,
                              hipStream_t stream)
{
    const float* x  = (const float*)d_in[0];
    const float* Wq = (const float*)d_in[1];
    const float* Wk = (const float*)d_in[2];
    const float* Wv = (const float*)d_in[3];
    const float* bq = (const float*)d_in[4];
    const float* bk = (const float*)d_in[5];
    const float* bv = (const float*)d_in[6];
    float* out = (float*)d_out;

    const size_t MK = (size_t)BB * SS * DD;
    char* ws = (char*)d_ws;
    short* xh  = (short*)ws; ws += MK * 2;
    short* xl  = (short*)ws; ws += MK * 2;
    short* wt  = (short*)ws; ws += 3ull * DD * DD * 2;
    short* qfp = (short*)ws; ws += MK * 2;
    short* kfp = (short*)ws; ws += MK * 2;
    short* vt  = (short*)ws; ws += MK * 2;
    const size_t fixed = (size_t)(ws - (char*)d_ws);

    int g = 4;
    while (g > 0 && fixed + (size_t)g * ((size_t)SS * SS * 2 + (size_t)SS * SS * 2) > ws_size)
        g >>= 1;
    if (g == 0) return;
    short* sc = (short*)ws;
    short* P  = (short*)(ws + (size_t)g * SS * SS * 2);

    cast_all<<<dim3(7168), 256, 0, stream>>>(x, Wq, Wk, Wv, xh, xl, wt);
    proj_all<<<dim3(12, 64), 256, 0, stream>>>(xh, xl, wt, bq, bk, bv,
                                               qfp, kfp, vt);

    for (int b0 = 0; b0 < BB; b0 += g) {
        const int gg = (b0 + g <= BB) ? g : (BB - b0);
        qkt128<<<dim3(16, 16, gg), 256, 0, stream>>>(
            qfp + (size_t)b0 * SS * DD, kfp + (size_t)b0 * SS * DD, sc, 256 * gg);
        softmax_rows<<<dim3(SS, gg), 256, 0, stream>>>(sc, P);
        pv_gemm<<<dim3(4, 32, gg), 256, 0, stream>>>(
            P, vt + ((size_t)b0 << 20), out + (size_t)b0 * SS * DD, 128 * gg);
    }
}

// Round 17
// 105.891 us; speedup vs baseline: 1.0540x; 1.0211x over previous
//
#include <hip/hip_runtime.h>
#include <hip/hip_bf16.h>
#include <hip/hip_fp16.h>

#define BB 4
#define SS 2048
#define DD 512

typedef short s16x8 __attribute__((ext_vector_type(8)));
typedef short s16x4 __attribute__((ext_vector_type(4)));
typedef float f32x4 __attribute__((ext_vector_type(4)));
typedef _Float16 f16x8 __attribute__((ext_vector_type(8)));

__device__ __forceinline__ short f2h(float f) {
    const _Float16 h = (_Float16)f;
    union { _Float16 h; short s; } u; u.h = h; return u.s;
}
__device__ __forceinline__ float h2f(short s) {
    union { short s; _Float16 h; } u; u.s = s; return (float)u.h;
}
__device__ __forceinline__ f16x8 as_h(s16x8 v) {
    union { s16x8 s; f16x8 h; } u; u.s = v; return u.h;
}

__device__ __forceinline__ void gload_lds16(const void* g, void* l) {
    __builtin_amdgcn_global_load_lds(
        (const __attribute__((address_space(1))) void*)g,
        (__attribute__((address_space(3))) void*)l, 16, 0, 0);
}

#define SB0 __builtin_amdgcn_sched_barrier(0)
#define LGKM0 asm volatile("s_waitcnt lgkmcnt(0)" ::: "memory")
#define VM0   asm volatile("s_waitcnt vmcnt(0)" ::: "memory")

// ---------------------------------------------------------------------------
// QK^T 128x128 tile, BK=32, 4 waves, 4 blocks/CU, fp16 single-pass,
// chunked XCD swizzle (R16-proven, unchanged).
// ---------------------------------------------------------------------------
__global__ __launch_bounds__(256, 4) void qkt128(
    const short* __restrict__ qf, const short* __restrict__ kf,
    short* __restrict__ outS, int nwg)
{
    __shared__ short lds[16384];  // [2 buf][2 arr][4096] = 32 KiB; ebuf reuse

    const int tid = threadIdx.x;
    const int wave = tid >> 6, lane = tid & 63;
    const int flat = blockIdx.x + 16 * blockIdx.y + 256 * blockIdx.z;
    const int w = (flat & 7) * (nwg >> 3) + (flat >> 3);   // chunked XCD map
    const int bm = ((w >> 4) & 15) * 128, bn = (w & 15) * 128;
    const long z = w >> 8;
    qf += z * (long)SS * DD; kf += z * (long)SS * DD;
    outS += z * (long)SS * SS;

    const int wm = (wave >> 1) * 64, wn = (wave & 1) * 64;
    const int lrow = lane & 15, lk16 = (lane >> 4) * 16;

    f32x4 acc[4][4] = {};

    auto base = [&](int buf, int arr) -> short* { return &lds[(buf * 2 + arr) * 4096]; };
    auto issue = [&](int buf, int arr, int k0) {
#pragma unroll
        for (int h = 0; h < 2; h++) {
            const int Lb = (h << 12) + (tid << 4);
            const int Ls = Lb ^ (((Lb >> 7) & 3) << 4);
            const int row = Ls >> 6, elem = (Ls & 63) >> 1;
            const short* s = arr ? kf : qf;
            const int rb = arr ? bn : bm;
            gload_lds16(s + (size_t)(rb + row) * DD + k0 + elem,
                        (char*)base(buf, arr) + Lb);
        }
    };
    auto rd = [&](int buf, int arr, int row) -> s16x8 {
        const int L = (row << 6) + lk16;
        const int Ls = L ^ (((L >> 7) & 3) << 4);
        return *(const s16x8*)((const char*)base(buf, arr) + Ls);
    };

#define QK_TILE(T, CUR, PREF)                                                    \
  {                                                                              \
    s16x8 a[4], b[4];                                                            \
    _Pragma("unroll")                                                            \
    for (int m = 0; m < 4; m++) a[m] = rd(CUR, 0, wm + m * 16 + lrow);           \
    _Pragma("unroll")                                                            \
    for (int n = 0; n < 4; n++) b[n] = rd(CUR, 1, wn + n * 16 + lrow);           \
    if (PREF) { issue((CUR) ^ 1, 1, ((T) + 1) * 32); SB0;                        \
                issue((CUR) ^ 1, 0, ((T) + 1) * 32); }                           \
    LGKM0; SB0;                                                                  \
    __builtin_amdgcn_s_setprio(1);                                               \
    _Pragma("unroll")                                                            \
    for (int m = 0; m < 4; m++) {                                                \
      _Pragma("unroll")                                                          \
      for (int n = 0; n < 4; n++)                                                \
        acc[m][n] = __builtin_amdgcn_mfma_f32_16x16x32_f16(                      \
            as_h(a[m]), as_h(b[n]), acc[m][n], 0, 0, 0);                         \
    }                                                                            \
    __builtin_amdgcn_s_setprio(0);                                               \
    if (PREF) { VM0; SB0; }                                                      \
    __builtin_amdgcn_s_barrier();                                                \
  }

    issue(0, 1, 0); issue(0, 0, 0);
    VM0;
    __builtin_amdgcn_s_barrier();

    for (int t = 0; t < 16; t += 2) {
        QK_TILE(t,     0, 1);
        QK_TILE(t + 1, 1, (t + 1) < 15);
    }
#undef QK_TILE

    __syncthreads();
    short* ebuf = &lds[0];
#pragma unroll
    for (int m = 0; m < 4; m++) {
#pragma unroll
        for (int n = 0; n < 4; n++) {
#pragma unroll
            for (int j = 0; j < 4; j++) {
                const int rl = wm + m * 16 + (lane >> 4) * 4 + j;
                const int cl = wn + n * 16 + lrow;
                ebuf[rl * 128 + (cl ^ ((rl & 7) << 3))] =
                    (short)__float2int_rn(acc[m][n][j] * 128.0f);
            }
        }
    }
    __syncthreads();
#pragma unroll
    for (int it = 0; it < 8; it++) {
        const int u = it * 256 + tid;
        const int r = u >> 4, c8 = (u & 15) * 8;
        const s16x8 val = *(const s16x8*)&ebuf[r * 128 + (c8 ^ ((r & 7) << 3))];
        *(s16x8*)&outS[(size_t)(bm + r) * SS + bn + c8] = val;
    }
}

// ---------------------------------------------------------------------------
// Unified projection, all-fp16, single-phase-per-tile + chunked XCD swizzle.
// CHANGE vs R16: Q is now 1-pass (xh only) — spends accuracy margin
// (0.073 -> ~0.09 predicted) for 20% less proj work. K stays 2-pass.
// ---------------------------------------------------------------------------
__global__ __launch_bounds__(256, 3) void proj_all(
    const short* __restrict__ xh, const short* __restrict__ xl,
    const short* __restrict__ wt,
    const float* __restrict__ bq, const float* __restrict__ bk,
    const float* __restrict__ bv,
    short* __restrict__ qfp, short* __restrict__ kfp, short* __restrict__ vt)
{
    __shared__ short lds[24576];

    const int tid = threadIdx.x;
    const int wave = tid >> 6, lane = tid & 63;
    const int flat = blockIdx.x + 12 * blockIdx.y;
    const int w = (flat & 7) * 96 + (flat >> 3);
    const int bxi = w % 12, byi = w / 12;
    const int wsel = bxi >> 2;
    const int bnl = (bxi & 3) * 128;
    const int bm = byi * 128;
    const bool lo = (wsel == 1);   // only K keeps the xl refinement pass
    const short* B0 = wt + (size_t)wsel * DD * DD;
    const float* bias = (wsel == 0) ? bq : (wsel == 1) ? bk : bv;

    f32x4 acc[4][4] = {};
    const int wm = (wave >> 1) * 64, wn = (wave & 1) * 64;
    const int lrow = lane & 15, lk16 = (lane >> 4) * 16;

    auto base = [&](int buf, int arr) -> short* { return &lds[(buf * 3 + arr) * 4096]; };
    auto issue = [&](int buf, int arr, int k0) {
#pragma unroll
        for (int h = 0; h < 2; h++) {
            const int Lb = (h << 12) + (tid << 4);
            const int Ls = Lb ^ (((Lb >> 7) & 3) << 4);
            const int row = Ls >> 6, elem = (Ls & 63) >> 1;
            const short* s = (arr == 0) ? xh : (arr == 1) ? xl : B0;
            const int rb = (arr < 2) ? bm : bnl;
            gload_lds16(s + (size_t)(rb + row) * DD + k0 + elem,
                        (char*)base(buf, arr) + Lb);
        }
    };
    auto rd = [&](int buf, int arr, int row) -> s16x8 {
        const int L = (row << 6) + lk16;
        const int Ls = L ^ (((L >> 7) & 3) << 4);
        return *(const s16x8*)((const char*)base(buf, arr) + Ls);
    };

#define PJ_TILE(T, CUR, PREF)                                                    \
  {                                                                              \
    s16x8 ah[4], al[4], b[4];                                                    \
    _Pragma("unroll")                                                            \
    for (int m = 0; m < 4; m++) ah[m] = rd(CUR, 0, wm + m * 16 + lrow);          \
    if (lo) {                                                                    \
      _Pragma("unroll")                                                          \
      for (int m = 0; m < 4; m++) al[m] = rd(CUR, 1, wm + m * 16 + lrow);        \
    }                                                                            \
    _Pragma("unroll")                                                            \
    for (int n = 0; n < 4; n++) b[n] = rd(CUR, 2, wn + n * 16 + lrow);           \
    if (PREF) {                                                                  \
      issue((CUR) ^ 1, 2, ((T) + 1) * 32); SB0;                                  \
      issue((CUR) ^ 1, 0, ((T) + 1) * 32);                                       \
      if (lo) issue((CUR) ^ 1, 1, ((T) + 1) * 32);                               \
    }                                                                            \
    LGKM0; SB0;                                                                  \
    __builtin_amdgcn_s_setprio(1);                                               \
    _Pragma("unroll")                                                            \
    for (int m = 0; m < 4; m++) {                                                \
      _Pragma("unroll")                                                          \
      for (int n = 0; n < 4; n++) {                                              \
        acc[m][n] = __builtin_amdgcn_mfma_f32_16x16x32_f16(                      \
            as_h(ah[m]), as_h(b[n]), acc[m][n], 0, 0, 0);                        \
        if (lo)                                                                  \
          acc[m][n] = __builtin_amdgcn_mfma_f32_16x16x32_f16(                    \
              as_h(al[m]), as_h(b[n]), acc[m][n], 0, 0, 0);                      \
      }                                                                          \
    }                                                                            \
    __builtin_amdgcn_s_setprio(0);                                               \
    if (PREF) { VM0; SB0; }                                                      \
    __builtin_amdgcn_s_barrier();                                                \
  }

    issue(0, 2, 0); issue(0, 0, 0);
    if (lo) issue(0, 1, 0);
    VM0;
    __builtin_amdgcn_s_barrier();

    for (int t = 0; t < 16; t += 2) {
        PJ_TILE(t,     0, 1);
        PJ_TILE(t + 1, 1, (t + 1) < 15);
    }
#undef PJ_TILE

    __syncthreads();
    short* cbuf = &lds[0];
#pragma unroll
    for (int m = 0; m < 4; m++) {
#pragma unroll
        for (int n = 0; n < 4; n++) {
#pragma unroll
            for (int j = 0; j < 4; j++) {
                const int rl = wm + m * 16 + (lane >> 4) * 4 + j;
                const int cl = wn + n * 16 + lrow;
                const float v = acc[m][n][j] + bias[bnl + cl];
                if (wsel < 2)
                    cbuf[rl * 128 + (cl ^ ((rl & 7) << 3))] = f2h(v);
                else
                    cbuf[cl * 128 + (rl ^ ((cl & 7) << 3))] = f2h(v);
            }
        }
    }
    __syncthreads();
    if (wsel < 2) {
        short* outp = wsel ? kfp : qfp;
#pragma unroll
        for (int it = 0; it < 8; it++) {
            const int u = it * 256 + tid;
            const int r = u >> 4, c8 = (u & 15) * 8;
            const s16x8 val = *(const s16x8*)&cbuf[r * 128 + (c8 ^ ((r & 7) << 3))];
            *(s16x8*)&outp[(size_t)(bm + r) * DD + bnl + c8] = val;
        }
    } else {
        const int b = bm >> 11, s0 = bm & 2047;
#pragma unroll
        for (int it = 0; it < 8; it++) {
            const int idx = it * 256 + tid;
            const int dd = idx >> 4, c8 = (idx & 15) * 8;
            const s16x8 val = *(const s16x8*)&cbuf[dd * 128 + (c8 ^ ((dd & 7) << 3))];
            *(s16x8*)&vt[((size_t)b << 20) + ((size_t)(bnl + dd) << 11) + s0 + c8] = val;
        }
    }
}

// ---------------------------------------------------------------------------
// PV GEMM fp16: 64x128 tile, BK=64 dbuf, single-phase-per-tile + chunked
// XCD swizzle (R13-proven, unchanged).
// ---------------------------------------------------------------------------
__global__ __launch_bounds__(256, 3) void pv_gemm(
    const short* __restrict__ P, const short* __restrict__ vt,
    float* __restrict__ out, int nwg)
{
    __shared__ short As[2][64 * 64];
    __shared__ short Bs[2][128 * 64];

    const int tid = threadIdx.x;
    const int wave = tid >> 6, lane = tid & 63;
    const int flat = blockIdx.x + 4 * blockIdx.y + 128 * blockIdx.z;
    const int w = (flat & 7) * (nwg >> 3) + (flat >> 3);
    const int bm = ((w >> 2) & 31) * 64, bn = (w & 3) * 128;
    const long z = w >> 7;
    P += z * (long)SS * SS;
    vt += z << 20;
    out += z * (long)SS * DD;

    f32x4 acc[2][4] = {};
    const int wm = (wave >> 1) * 32, wn = (wave & 1) * 64;
    const int lrow = lane & 15, lk = (lane >> 4) * 8;

    auto swz = [](int L) { return L ^ (((L >> 7) & 7) << 4); };
    auto issueA = [&](int buf, int k0) {
#pragma unroll
        for (int h = 0; h < 2; h++) {
            const int L = (h << 12) + (tid << 4);
            const int Ls = swz(L);
            const int row = Ls >> 7, col = (Ls & 127) >> 1;
            gload_lds16(P + (size_t)(bm + row) * SS + k0 + col, (char*)&As[buf][0] + L);
        }
    };
    auto issueB = [&](int buf, int k0) {
#pragma unroll
        for (int h = 0; h < 4; h++) {
            const int L = (h << 12) + (tid << 4);
            const int Ls = swz(L);
            const int row = Ls >> 7, col = (Ls & 127) >> 1;
            gload_lds16(vt + ((size_t)(bn + row) << 11) + k0 + col, (char*)&Bs[buf][0] + L);
        }
    };

#define PV_TILE(T, CUR, PREF)                                                    \
  {                                                                              \
    s16x8 a[2][2], b[2][4];                                                      \
    _Pragma("unroll")                                                            \
    for (int kx = 0; kx < 2; kx++) {                                             \
      _Pragma("unroll")                                                          \
      for (int m = 0; m < 2; m++)                                                \
        a[kx][m] = *(const s16x8*)((const char*)&As[CUR][0] +                    \
                   swz(((wm + m * 16 + lrow) * 64 + kx * 32 + lk) * 2));         \
      _Pragma("unroll")                                                          \
      for (int n = 0; n < 4; n++)                                                \
        b[kx][n] = *(const s16x8*)((const char*)&Bs[CUR][0] +                    \
                   swz(((wn + n * 16 + lrow) * 64 + kx * 32 + lk) * 2));         \
    }                                                                            \
    if (PREF) { issueB((CUR) ^ 1, ((T) + 1) * 64); SB0;                          \
                issueA((CUR) ^ 1, ((T) + 1) * 64); }                             \
    LGKM0; SB0;                                                                  \
    __builtin_amdgcn_s_setprio(1);                                               \
    _Pragma("unroll")                                                            \
    for (int kx = 0; kx < 2; kx++) {                                             \
      _Pragma("unroll")                                                          \
      for (int m = 0; m < 2; m++) {                                              \
        _Pragma("unroll")                                                        \
        for (int n = 0; n < 4; n++)                                              \
          acc[m][n] = __builtin_amdgcn_mfma_f32_16x16x32_f16(                    \
              as_h(a[kx][m]), as_h(b[kx][n]), acc[m][n], 0, 0, 0);               \
      }                                                                          \
    }                                                                            \
    __builtin_amdgcn_s_setprio(0);                                               \
    if (PREF) { VM0; SB0; }                                                      \
    __builtin_amdgcn_s_barrier();                                                \
  }

    issueB(0, 0); issueA(0, 0);
    VM0;
    __builtin_amdgcn_s_barrier();

    for (int t = 0; t < 32; t += 2) {
        PV_TILE(t,     0, 1);
        PV_TILE(t + 1, 1, (t + 1) < 31);
    }
#undef PV_TILE

#pragma unroll
    for (int m = 0; m < 2; m++) {
#pragma unroll
        for (int n = 0; n < 4; n++) {
#pragma unroll
            for (int j = 0; j < 4; j++) {
                const int row = bm + wm + m * 16 + (lane >> 4) * 4 + j;
                const int col = bn + wn + n * 16 + lrow;
                out[(size_t)row * DD + col] = acc[m][n][j];
            }
        }
    }
}

// merged casts (R9-proven, unchanged)
__global__ __launch_bounds__(256) void cast_all(
    const float* __restrict__ x,
    const float* __restrict__ wq, const float* __restrict__ wk,
    const float* __restrict__ wv,
    short* __restrict__ xh, short* __restrict__ xl,
    short* __restrict__ wt)
{
    const int bid = blockIdx.x;
    if (bid < 4096) {
        const int i = bid * 256 + threadIdx.x;
        const float4 v = ((const float4*)x)[i];
        const float vv[4] = {v.x, v.y, v.z, v.w};
        s16x4 h, l;
#pragma unroll
        for (int j = 0; j < 4; j++) {
            const short hh = f2h(vv[j]);
            h[j] = hh;
            l[j] = f2h(vv[j] - h2f(hh));
        }
        ((s16x4*)xh)[i] = h;
        ((s16x4*)xl)[i] = l;
    } else {
        const int t = (bid - 4096) * 256 + threadIdx.x;
        const int w = t >> 18;
        const int r = t & 262143;
        const float* src = (w == 0) ? wq : ((w == 1) ? wk : wv);
        const float v = src[r];
        const int k = r >> 9, n = r & 511;
        wt[((size_t)w << 18) + ((size_t)n << 9) + k] = f2h(v);
    }
}

// softmax over int16 scores (scale 1/128), fp16 P out (R10-proven, unchanged)
__global__ __launch_bounds__(256) void softmax_rows(
    const short* __restrict__ S, short* __restrict__ P)
{
    const int row = blockIdx.x;
    const long z = blockIdx.y;
    const short* s = S + z * (long)SS * SS + (long)row * SS;
    short* p = P + z * (long)SS * SS + (long)row * SS;
    const int tid = threadIdx.x;

    const s16x8 raw = ((const s16x8*)s)[tid];
    float v[8];
#pragma unroll
    for (int j = 0; j < 8; j++) v[j] = (float)(int)raw[j] * 0.0078125f;

    float m = v[0];
#pragma unroll
    for (int j = 1; j < 8; j++) m = fmaxf(m, v[j]);
#pragma unroll
    for (int off = 32; off >= 1; off >>= 1) m = fmaxf(m, __shfl_xor(m, off));
    __shared__ float redm[4], reds[4];
    if ((tid & 63) == 0) redm[tid >> 6] = m;
    __syncthreads();
    m = fmaxf(fmaxf(redm[0], redm[1]), fmaxf(redm[2], redm[3]));

    float e[8], sum = 0.f;
#pragma unroll
    for (int j = 0; j < 8; j++) { e[j] = __expf(v[j] - m); sum += e[j]; }
#pragma unroll
    for (int off = 32; off >= 1; off >>= 1) sum += __shfl_xor(sum, off);
    if ((tid & 63) == 0) reds[tid >> 6] = sum;
    __syncthreads();
    sum = reds[0] + reds[1] + reds[2] + reds[3];
    const float inv = 1.0f / sum;

    s16x8 o;
#pragma unroll
    for (int j = 0; j < 8; j++) o[j] = f2h(e[j] * inv);
    ((s16x8*)p)[tid] = o;
}

extern "C" void kernel_launch(void* const* d_in, const int* in_sizes, int n_in,
                              void* d_out, int out_size, void* d_ws, size_t ws_size,
                              hipStream_t stream)
{
    const float* x  = (const float*)d_in[0];
    const float* Wq = (const float*)d_in[1];
    const float* Wk = (const float*)d_in[2];
    const float* Wv = (const float*)d_in[3];
    const float* bq = (const float*)d_in[4];
    const float* bk = (const float*)d_in[5];
    const float* bv = (const float*)d_in[6];
    float* out = (float*)d_out;

    const size_t MK = (size_t)BB * SS * DD;
    char* ws = (char*)d_ws;
    short* xh  = (short*)ws; ws += MK * 2;
    short* xl  = (short*)ws; ws += MK * 2;
    short* wt  = (short*)ws; ws += 3ull * DD * DD * 2;
    short* qfp = (short*)ws; ws += MK * 2;
    short* kfp = (short*)ws; ws += MK * 2;
    short* vt  = (short*)ws; ws += MK * 2;
    const size_t fixed = (size_t)(ws - (char*)d_ws);

    int g = 4;
    while (g > 0 && fixed + (size_t)g * ((size_t)SS * SS * 2 + (size_t)SS * SS * 2) > ws_size)
        g >>= 1;
    if (g == 0) return;
    short* sc = (short*)ws;
    short* P  = (short*)(ws + (size_t)g * SS * SS * 2);

    cast_all<<<dim3(7168), 256, 0, stream>>>(x, Wq, Wk, Wv, xh, xl, wt);
    proj_all<<<dim3(12, 64), 256, 0, stream>>>(xh, xl, wt, bq, bk, bv,
                                               qfp, kfp, vt);

    for (int b0 = 0; b0 < BB; b0 += g) {
        const int gg = (b0 + g <= BB) ? g : (BB - b0);
        qkt128<<<dim3(16, 16, gg), 256, 0, stream>>>(
            qfp + (size_t)b0 * SS * DD, kfp + (size_t)b0 * SS * DD, sc, 256 * gg);
        softmax_rows<<<dim3(SS, gg), 256, 0, stream>>>(sc, P);
        pv_gemm<<<dim3(4, 32, gg), 256, 0, stream>>>(
            P, vt + ((size_t)b0 << 20), out + (size_t)b0 * SS * DD, 128 * gg);
    }
}

// Round 18
// 100.919 us; speedup vs baseline: 1.1060x; 1.0493x over previous
//
#include <hip/hip_runtime.h>
#include <hip/hip_bf16.h>
#include <hip/hip_fp16.h>

#define BB 4
#define SS 2048
#define DD 512

typedef short s16x8 __attribute__((ext_vector_type(8)));
typedef short s16x4 __attribute__((ext_vector_type(4)));
typedef float f32x4 __attribute__((ext_vector_type(4)));
typedef _Float16 f16x8 __attribute__((ext_vector_type(8)));

__device__ __forceinline__ short f2h(float f) {
    const _Float16 h = (_Float16)f;
    union { _Float16 h; short s; } u; u.h = h; return u.s;
}
__device__ __forceinline__ f16x8 as_h(s16x8 v) {
    union { s16x8 s; f16x8 h; } u; u.s = v; return u.h;
}

__device__ __forceinline__ void gload_lds16(const void* g, void* l) {
    __builtin_amdgcn_global_load_lds(
        (const __attribute__((address_space(1))) void*)g,
        (__attribute__((address_space(3))) void*)l, 16, 0, 0);
}

#define SB0 __builtin_amdgcn_sched_barrier(0)
#define LGKM0 asm volatile("s_waitcnt lgkmcnt(0)" ::: "memory")
#define VM0   asm volatile("s_waitcnt vmcnt(0)" ::: "memory")

// ---------------------------------------------------------------------------
// QK^T 128x128 tile, BK=32, 4 waves, 4 blocks/CU, fp16 single-pass,
// chunked XCD swizzle (R16-proven, unchanged).
// ---------------------------------------------------------------------------
__global__ __launch_bounds__(256, 4) void qkt128(
    const short* __restrict__ qf, const short* __restrict__ kf,
    short* __restrict__ outS, int nwg)
{
    __shared__ short lds[16384];  // [2 buf][2 arr][4096] = 32 KiB; ebuf reuse

    const int tid = threadIdx.x;
    const int wave = tid >> 6, lane = tid & 63;
    const int flat = blockIdx.x + 16 * blockIdx.y + 256 * blockIdx.z;
    const int w = (flat & 7) * (nwg >> 3) + (flat >> 3);   // chunked XCD map
    const int bm = ((w >> 4) & 15) * 128, bn = (w & 15) * 128;
    const long z = w >> 8;
    qf += z * (long)SS * DD; kf += z * (long)SS * DD;
    outS += z * (long)SS * SS;

    const int wm = (wave >> 1) * 64, wn = (wave & 1) * 64;
    const int lrow = lane & 15, lk16 = (lane >> 4) * 16;

    f32x4 acc[4][4] = {};

    auto base = [&](int buf, int arr) -> short* { return &lds[(buf * 2 + arr) * 4096]; };
    auto issue = [&](int buf, int arr, int k0) {
#pragma unroll
        for (int h = 0; h < 2; h++) {
            const int Lb = (h << 12) + (tid << 4);
            const int Ls = Lb ^ (((Lb >> 7) & 3) << 4);
            const int row = Ls >> 6, elem = (Ls & 63) >> 1;
            const short* s = arr ? kf : qf;
            const int rb = arr ? bn : bm;
            gload_lds16(s + (size_t)(rb + row) * DD + k0 + elem,
                        (char*)base(buf, arr) + Lb);
        }
    };
    auto rd = [&](int buf, int arr, int row) -> s16x8 {
        const int L = (row << 6) + lk16;
        const int Ls = L ^ (((L >> 7) & 3) << 4);
        return *(const s16x8*)((const char*)base(buf, arr) + Ls);
    };

#define QK_TILE(T, CUR, PREF)                                                    \
  {                                                                              \
    s16x8 a[4], b[4];                                                            \
    _Pragma("unroll")                                                            \
    for (int m = 0; m < 4; m++) a[m] = rd(CUR, 0, wm + m * 16 + lrow);           \
    _Pragma("unroll")                                                            \
    for (int n = 0; n < 4; n++) b[n] = rd(CUR, 1, wn + n * 16 + lrow);           \
    if (PREF) { issue((CUR) ^ 1, 1, ((T) + 1) * 32); SB0;                        \
                issue((CUR) ^ 1, 0, ((T) + 1) * 32); }                           \
    LGKM0; SB0;                                                                  \
    __builtin_amdgcn_s_setprio(1);                                               \
    _Pragma("unroll")                                                            \
    for (int m = 0; m < 4; m++) {                                                \
      _Pragma("unroll")                                                          \
      for (int n = 0; n < 4; n++)                                                \
        acc[m][n] = __builtin_amdgcn_mfma_f32_16x16x32_f16(                      \
            as_h(a[m]), as_h(b[n]), acc[m][n], 0, 0, 0);                         \
    }                                                                            \
    __builtin_amdgcn_s_setprio(0);                                               \
    if (PREF) { VM0; SB0; }                                                      \
    __builtin_amdgcn_s_barrier();                                                \
  }

    issue(0, 1, 0); issue(0, 0, 0);
    VM0;
    __builtin_amdgcn_s_barrier();

    for (int t = 0; t < 16; t += 2) {
        QK_TILE(t,     0, 1);
        QK_TILE(t + 1, 1, (t + 1) < 15);
    }
#undef QK_TILE

    __syncthreads();
    short* ebuf = &lds[0];
#pragma unroll
    for (int m = 0; m < 4; m++) {
#pragma unroll
        for (int n = 0; n < 4; n++) {
#pragma unroll
            for (int j = 0; j < 4; j++) {
                const int rl = wm + m * 16 + (lane >> 4) * 4 + j;
                const int cl = wn + n * 16 + lrow;
                ebuf[rl * 128 + (cl ^ ((rl & 7) << 3))] =
                    (short)__float2int_rn(acc[m][n][j] * 128.0f);
            }
        }
    }
    __syncthreads();
#pragma unroll
    for (int it = 0; it < 8; it++) {
        const int u = it * 256 + tid;
        const int r = u >> 4, c8 = (u & 15) * 8;
        const s16x8 val = *(const s16x8*)&ebuf[r * 128 + (c8 ^ ((r & 7) << 3))];
        *(s16x8*)&outS[(size_t)(bm + r) * SS + bn + c8] = val;
    }
}

// ---------------------------------------------------------------------------
// Unified projection, all-fp16 1-PASS for Q, K, and V (accuracy budget spent:
// measured 0.073->0.083 for Q 1-pass; K symmetric -> predicted ~0.092).
// 2 staged planes {x, W}, 32 KiB LDS -> 4 blocks/CU. Chunked XCD swizzle.
// ---------------------------------------------------------------------------
__global__ __launch_bounds__(256, 4) void proj_all(
    const short* __restrict__ xh, const short* __restrict__ wt,
    const float* __restrict__ bq, const float* __restrict__ bk,
    const float* __restrict__ bv,
    short* __restrict__ qfp, short* __restrict__ kfp, short* __restrict__ vt)
{
    __shared__ short lds[16384];  // [2 buf][2 arr][4096] = 32 KiB; cbuf reuse

    const int tid = threadIdx.x;
    const int wave = tid >> 6, lane = tid & 63;
    const int flat = blockIdx.x + 12 * blockIdx.y;
    const int w = (flat & 7) * 96 + (flat >> 3);
    const int bxi = w % 12, byi = w / 12;
    const int wsel = bxi >> 2;
    const int bnl = (bxi & 3) * 128;
    const int bm = byi * 128;
    const short* B0 = wt + (size_t)wsel * DD * DD;
    const float* bias = (wsel == 0) ? bq : (wsel == 1) ? bk : bv;

    f32x4 acc[4][4] = {};
    const int wm = (wave >> 1) * 64, wn = (wave & 1) * 64;
    const int lrow = lane & 15, lk16 = (lane >> 4) * 16;

    auto base = [&](int buf, int arr) -> short* { return &lds[(buf * 2 + arr) * 4096]; };
    auto issue = [&](int buf, int arr, int k0) {
#pragma unroll
        for (int h = 0; h < 2; h++) {
            const int Lb = (h << 12) + (tid << 4);
            const int Ls = Lb ^ (((Lb >> 7) & 3) << 4);
            const int row = Ls >> 6, elem = (Ls & 63) >> 1;
            const short* s = arr ? B0 : xh;
            const int rb = arr ? bnl : bm;
            gload_lds16(s + (size_t)(rb + row) * DD + k0 + elem,
                        (char*)base(buf, arr) + Lb);
        }
    };
    auto rd = [&](int buf, int arr, int row) -> s16x8 {
        const int L = (row << 6) + lk16;
        const int Ls = L ^ (((L >> 7) & 3) << 4);
        return *(const s16x8*)((const char*)base(buf, arr) + Ls);
    };

#define PJ_TILE(T, CUR, PREF)                                                    \
  {                                                                              \
    s16x8 a[4], b[4];                                                            \
    _Pragma("unroll")                                                            \
    for (int m = 0; m < 4; m++) a[m] = rd(CUR, 0, wm + m * 16 + lrow);           \
    _Pragma("unroll")                                                            \
    for (int n = 0; n < 4; n++) b[n] = rd(CUR, 1, wn + n * 16 + lrow);           \
    if (PREF) { issue((CUR) ^ 1, 1, ((T) + 1) * 32); SB0;                        \
                issue((CUR) ^ 1, 0, ((T) + 1) * 32); }                           \
    LGKM0; SB0;                                                                  \
    __builtin_amdgcn_s_setprio(1);                                               \
    _Pragma("unroll")                                                            \
    for (int m = 0; m < 4; m++) {                                                \
      _Pragma("unroll")                                                          \
      for (int n = 0; n < 4; n++)                                                \
        acc[m][n] = __builtin_amdgcn_mfma_f32_16x16x32_f16(                      \
            as_h(a[m]), as_h(b[n]), acc[m][n], 0, 0, 0);                         \
    }                                                                            \
    __builtin_amdgcn_s_setprio(0);                                               \
    if (PREF) { VM0; SB0; }                                                      \
    __builtin_amdgcn_s_barrier();                                                \
  }

    issue(0, 1, 0); issue(0, 0, 0);
    VM0;
    __builtin_amdgcn_s_barrier();

    for (int t = 0; t < 16; t += 2) {
        PJ_TILE(t,     0, 1);
        PJ_TILE(t + 1, 1, (t + 1) < 15);
    }
#undef PJ_TILE

    __syncthreads();
    short* cbuf = &lds[0];  // 32 KiB = 128*128 shorts
#pragma unroll
    for (int m = 0; m < 4; m++) {
#pragma unroll
        for (int n = 0; n < 4; n++) {
#pragma unroll
            for (int j = 0; j < 4; j++) {
                const int rl = wm + m * 16 + (lane >> 4) * 4 + j;
                const int cl = wn + n * 16 + lrow;
                const float v = acc[m][n][j] + bias[bnl + cl];
                if (wsel < 2)
                    cbuf[rl * 128 + (cl ^ ((rl & 7) << 3))] = f2h(v);
                else
                    cbuf[cl * 128 + (rl ^ ((cl & 7) << 3))] = f2h(v);
            }
        }
    }
    __syncthreads();
    if (wsel < 2) {
        short* outp = wsel ? kfp : qfp;
#pragma unroll
        for (int it = 0; it < 8; it++) {
            const int u = it * 256 + tid;
            const int r = u >> 4, c8 = (u & 15) * 8;
            const s16x8 val = *(const s16x8*)&cbuf[r * 128 + (c8 ^ ((r & 7) << 3))];
            *(s16x8*)&outp[(size_t)(bm + r) * DD + bnl + c8] = val;
        }
    } else {
        const int b = bm >> 11, s0 = bm & 2047;
#pragma unroll
        for (int it = 0; it < 8; it++) {
            const int idx = it * 256 + tid;
            const int dd = idx >> 4, c8 = (idx & 15) * 8;
            const s16x8 val = *(const s16x8*)&cbuf[dd * 128 + (c8 ^ ((dd & 7) << 3))];
            *(s16x8*)&vt[((size_t)b << 20) + ((size_t)(bnl + dd) << 11) + s0 + c8] = val;
        }
    }
}

// ---------------------------------------------------------------------------
// PV GEMM fp16: 64x128 tile, BK=64 dbuf, single-phase-per-tile + chunked
// XCD swizzle (R13-proven, unchanged).
// ---------------------------------------------------------------------------
__global__ __launch_bounds__(256, 3) void pv_gemm(
    const short* __restrict__ P, const short* __restrict__ vt,
    float* __restrict__ out, int nwg)
{
    __shared__ short As[2][64 * 64];
    __shared__ short Bs[2][128 * 64];

    const int tid = threadIdx.x;
    const int wave = tid >> 6, lane = tid & 63;
    const int flat = blockIdx.x + 4 * blockIdx.y + 128 * blockIdx.z;
    const int w = (flat & 7) * (nwg >> 3) + (flat >> 3);
    const int bm = ((w >> 2) & 31) * 64, bn = (w & 3) * 128;
    const long z = w >> 7;
    P += z * (long)SS * SS;
    vt += z << 20;
    out += z * (long)SS * DD;

    f32x4 acc[2][4] = {};
    const int wm = (wave >> 1) * 32, wn = (wave & 1) * 64;
    const int lrow = lane & 15, lk = (lane >> 4) * 8;

    auto swz = [](int L) { return L ^ (((L >> 7) & 7) << 4); };
    auto issueA = [&](int buf, int k0) {
#pragma unroll
        for (int h = 0; h < 2; h++) {
            const int L = (h << 12) + (tid << 4);
            const int Ls = swz(L);
            const int row = Ls >> 7, col = (Ls & 127) >> 1;
            gload_lds16(P + (size_t)(bm + row) * SS + k0 + col, (char*)&As[buf][0] + L);
        }
    };
    auto issueB = [&](int buf, int k0) {
#pragma unroll
        for (int h = 0; h < 4; h++) {
            const int L = (h << 12) + (tid << 4);
            const int Ls = swz(L);
            const int row = Ls >> 7, col = (Ls & 127) >> 1;
            gload_lds16(vt + ((size_t)(bn + row) << 11) + k0 + col, (char*)&Bs[buf][0] + L);
        }
    };

#define PV_TILE(T, CUR, PREF)                                                    \
  {                                                                              \
    s16x8 a[2][2], b[2][4];                                                      \
    _Pragma("unroll")                                                            \
    for (int kx = 0; kx < 2; kx++) {                                             \
      _Pragma("unroll")                                                          \
      for (int m = 0; m < 2; m++)                                                \
        a[kx][m] = *(const s16x8*)((const char*)&As[CUR][0] +                    \
                   swz(((wm + m * 16 + lrow) * 64 + kx * 32 + lk) * 2));         \
      _Pragma("unroll")                                                          \
      for (int n = 0; n < 4; n++)                                                \
        b[kx][n] = *(const s16x8*)((const char*)&Bs[CUR][0] +                    \
                   swz(((wn + n * 16 + lrow) * 64 + kx * 32 + lk) * 2));         \
    }                                                                            \
    if (PREF) { issueB((CUR) ^ 1, ((T) + 1) * 64); SB0;                          \
                issueA((CUR) ^ 1, ((T) + 1) * 64); }                             \
    LGKM0; SB0;                                                                  \
    __builtin_amdgcn_s_setprio(1);                                               \
    _Pragma("unroll")                                                            \
    for (int kx = 0; kx < 2; kx++) {                                             \
      _Pragma("unroll")                                                          \
      for (int m = 0; m < 2; m++) {                                              \
        _Pragma("unroll")                                                        \
        for (int n = 0; n < 4; n++)                                              \
          acc[m][n] = __builtin_amdgcn_mfma_f32_16x16x32_f16(                    \
              as_h(a[kx][m]), as_h(b[kx][n]), acc[m][n], 0, 0, 0);               \
      }                                                                          \
    }                                                                            \
    __builtin_amdgcn_s_setprio(0);                                               \
    if (PREF) { VM0; SB0; }                                                      \
    __builtin_amdgcn_s_barrier();                                                \
  }

    issueB(0, 0); issueA(0, 0);
    VM0;
    __builtin_amdgcn_s_barrier();

    for (int t = 0; t < 32; t += 2) {
        PV_TILE(t,     0, 1);
        PV_TILE(t + 1, 1, (t + 1) < 31);
    }
#undef PV_TILE

#pragma unroll
    for (int m = 0; m < 2; m++) {
#pragma unroll
        for (int n = 0; n < 4; n++) {
#pragma unroll
            for (int j = 0; j < 4; j++) {
                const int row = bm + wm + m * 16 + (lane >> 4) * 4 + j;
                const int col = bn + wn + n * 16 + lrow;
                out[(size_t)row * DD + col] = acc[m][n][j];
            }
        }
    }
}

// merged casts: blocks [0,4096) cast x to fp16 (single plane);
// [4096,7168) transpose W into single fp16 plane.
__global__ __launch_bounds__(256) void cast_all(
    const float* __restrict__ x,
    const float* __restrict__ wq, const float* __restrict__ wk,
    const float* __restrict__ wv,
    short* __restrict__ xh, short* __restrict__ wt)
{
    const int bid = blockIdx.x;
    if (bid < 4096) {
        const int i = bid * 256 + threadIdx.x;
        const float4 v = ((const float4*)x)[i];
        const float vv[4] = {v.x, v.y, v.z, v.w};
        s16x4 h;
#pragma unroll
        for (int j = 0; j < 4; j++) h[j] = f2h(vv[j]);
        ((s16x4*)xh)[i] = h;
    } else {
        const int t = (bid - 4096) * 256 + threadIdx.x;
        const int w = t >> 18;
        const int r = t & 262143;
        const float* src = (w == 0) ? wq : ((w == 1) ? wk : wv);
        const float v = src[r];
        const int k = r >> 9, n = r & 511;
        wt[((size_t)w << 18) + ((size_t)n << 9) + k] = f2h(v);
    }
}

// softmax over int16 scores (scale 1/128), fp16 P out (R10-proven, unchanged)
__global__ __launch_bounds__(256) void softmax_rows(
    const short* __restrict__ S, short* __restrict__ P)
{
    const int row = blockIdx.x;
    const long z = blockIdx.y;
    const short* s = S + z * (long)SS * SS + (long)row * SS;
    short* p = P + z * (long)SS * SS + (long)row * SS;
    const int tid = threadIdx.x;

    const s16x8 raw = ((const s16x8*)s)[tid];
    float v[8];
#pragma unroll
    for (int j = 0; j < 8; j++) v[j] = (float)(int)raw[j] * 0.0078125f;

    float m = v[0];
#pragma unroll
    for (int j = 1; j < 8; j++) m = fmaxf(m, v[j]);
#pragma unroll
    for (int off = 32; off >= 1; off >>= 1) m = fmaxf(m, __shfl_xor(m, off));
    __shared__ float redm[4], reds[4];
    if ((tid & 63) == 0) redm[tid >> 6] = m;
    __syncthreads();
    m = fmaxf(fmaxf(redm[0], redm[1]), fmaxf(redm[2], redm[3]));

    float e[8], sum = 0.f;
#pragma unroll
    for (int j = 0; j < 8; j++) { e[j] = __expf(v[j] - m); sum += e[j]; }
#pragma unroll
    for (int off = 32; off >= 1; off >>= 1) sum += __shfl_xor(sum, off);
    if ((tid & 63) == 0) reds[tid >> 6] = sum;
    __syncthreads();
    sum = reds[0] + reds[1] + reds[2] + reds[3];
    const float inv = 1.0f / sum;

    s16x8 o;
#pragma unroll
    for (int j = 0; j < 8; j++) o[j] = f2h(e[j] * inv);
    ((s16x8*)p)[tid] = o;
}

extern "C" void kernel_launch(void* const* d_in, const int* in_sizes, int n_in,
                              void* d_out, int out_size, void* d_ws, size_t ws_size,
                              hipStream_t stream)
{
    const float* x  = (const float*)d_in[0];
    const float* Wq = (const float*)d_in[1];
    const float* Wk = (const float*)d_in[2];
    const float* Wv = (const float*)d_in[3];
    const float* bq = (const float*)d_in[4];
    const float* bk = (const float*)d_in[5];
    const float* bv = (const float*)d_in[6];
    float* out = (float*)d_out;

    const size_t MK = (size_t)BB * SS * DD;
    char* ws = (char*)d_ws;
    short* xh  = (short*)ws; ws += MK * 2;
    short* wt  = (short*)ws; ws += 3ull * DD * DD * 2;
    short* qfp = (short*)ws; ws += MK * 2;
    short* kfp = (short*)ws; ws += MK * 2;
    short* vt  = (short*)ws; ws += MK * 2;
    const size_t fixed = (size_t)(ws - (char*)d_ws);

    int g = 4;
    while (g > 0 && fixed + (size_t)g * ((size_t)SS * SS * 2 + (size_t)SS * SS * 2) > ws_size)
        g >>= 1;
    if (g == 0) return;
    short* sc = (short*)ws;
    short* P  = (short*)(ws + (size_t)g * SS * SS * 2);

    cast_all<<<dim3(7168), 256, 0, stream>>>(x, Wq, Wk, Wv, xh, wt);
    proj_all<<<dim3(12, 64), 256, 0, stream>>>(xh, wt, bq, bk, bv,
                                               qfp, kfp, vt);

    for (int b0 = 0; b0 < BB; b0 += g) {
        const int gg = (b0 + g <= BB) ? g : (BB - b0);
        qkt128<<<dim3(16, 16, gg), 256, 0, stream>>>(
            qfp + (size_t)b0 * SS * DD, kfp + (size_t)b0 * SS * DD, sc, 256 * gg);
        softmax_rows<<<dim3(SS, gg), 256, 0, stream>>>(sc, P);
        pv_gemm<<<dim3(4, 32, gg), 256, 0, stream>>>(
            P, vt + ((size_t)b0 << 20), out + (size_t)b0 * SS * DD, 128 * gg);
    }
}

// Round 19
// 99.715 us; speedup vs baseline: 1.1193x; 1.0121x over previous
//
#include <hip/hip_runtime.h>
#include <hip/hip_bf16.h>
#include <hip/hip_fp16.h>

#define BB 4
#define SS 2048
#define DD 512

typedef short s16x8 __attribute__((ext_vector_type(8)));
typedef short s16x4 __attribute__((ext_vector_type(4)));
typedef float f32x4 __attribute__((ext_vector_type(4)));
typedef _Float16 f16x8 __attribute__((ext_vector_type(8)));

__device__ __forceinline__ short f2h(float f) {
    const _Float16 h = (_Float16)f;
    union { _Float16 h; short s; } u; u.h = h; return u.s;
}
__device__ __forceinline__ f16x8 as_h(s16x8 v) {
    union { s16x8 s; f16x8 h; } u; u.s = v; return u.h;
}

__device__ __forceinline__ void gload_lds16(const void* g, void* l) {
    __builtin_amdgcn_global_load_lds(
        (const __attribute__((address_space(1))) void*)g,
        (__attribute__((address_space(3))) void*)l, 16, 0, 0);
}

#define SB0 __builtin_amdgcn_sched_barrier(0)
#define LGKM0 asm volatile("s_waitcnt lgkmcnt(0)" ::: "memory")
#define VM0   asm volatile("s_waitcnt vmcnt(0)" ::: "memory")
#define VM4   asm volatile("s_waitcnt vmcnt(4)" ::: "memory")

// ---------------------------------------------------------------------------
// QK^T 128x128 tile, BK=32, 4 waves, fp16 single-pass, chunked XCD swizzle.
// TRIPLE-buffered with counted vmcnt (T4): tile t reads buf(t%3), issues
// t+2's loads, MFMAs, then [vmcnt(4) -> barrier] — t+1 landed for ALL waves,
// t+2's 4 loads stay in flight ACROSS the barrier (never drain to 0).
// 48 KiB LDS -> 3 blocks/CU. int16 scores via cbuf repack.
// ---------------------------------------------------------------------------
__global__ __launch_bounds__(256, 3) void qkt128(
    const short* __restrict__ qf, const short* __restrict__ kf,
    short* __restrict__ outS, int nwg)
{
    __shared__ short lds[24576];  // [3 buf][2 arr][4096] = 48 KiB; ebuf reuse

    const int tid = threadIdx.x;
    const int wave = tid >> 6, lane = tid & 63;
    const int flat = blockIdx.x + 16 * blockIdx.y + 256 * blockIdx.z;
    const int w = (flat & 7) * (nwg >> 3) + (flat >> 3);   // chunked XCD map
    const int bm = ((w >> 4) & 15) * 128, bn = (w & 15) * 128;
    const long z = w >> 8;
    qf += z * (long)SS * DD; kf += z * (long)SS * DD;
    outS += z * (long)SS * SS;

    const int wm = (wave >> 1) * 64, wn = (wave & 1) * 64;
    const int lrow = lane & 15, lk16 = (lane >> 4) * 16;

    f32x4 acc[4][4] = {};

    auto base = [&](int buf, int arr) -> short* { return &lds[(buf * 2 + arr) * 4096]; };
    auto issue = [&](int buf, int arr, int k0) {
#pragma unroll
        for (int h = 0; h < 2; h++) {
            const int Lb = (h << 12) + (tid << 4);
            const int Ls = Lb ^ (((Lb >> 7) & 3) << 4);
            const int row = Ls >> 6, elem = (Ls & 63) >> 1;
            const short* s = arr ? kf : qf;
            const int rb = arr ? bn : bm;
            gload_lds16(s + (size_t)(rb + row) * DD + k0 + elem,
                        (char*)base(buf, arr) + Lb);
        }
    };
    auto rd = [&](int buf, int arr, int row) -> s16x8 {
        const int L = (row << 6) + lk16;
        const int Ls = L ^ (((L >> 7) & 3) << 4);
        return *(const s16x8*)((const char*)base(buf, arr) + Ls);
    };

// T: tile index. CUR = T%3, NX2 = (T+2)%3. Prefetch while T+2 < 16.
#define QK_TILE(T, CUR, NX2)                                                     \
  {                                                                              \
    s16x8 a[4], b[4];                                                            \
    _Pragma("unroll")                                                            \
    for (int m = 0; m < 4; m++) a[m] = rd(CUR, 0, wm + m * 16 + lrow);           \
    _Pragma("unroll")                                                            \
    for (int n = 0; n < 4; n++) b[n] = rd(CUR, 1, wn + n * 16 + lrow);           \
    if ((T) + 2 < 16) { issue(NX2, 1, ((T) + 2) * 32); SB0;                      \
                        issue(NX2, 0, ((T) + 2) * 32); }                         \
    LGKM0; SB0;                                                                  \
    __builtin_amdgcn_s_setprio(1);                                               \
    _Pragma("unroll")                                                            \
    for (int m = 0; m < 4; m++) {                                                \
      _Pragma("unroll")                                                          \
      for (int n = 0; n < 4; n++)                                                \
        acc[m][n] = __builtin_amdgcn_mfma_f32_16x16x32_f16(                      \
            as_h(a[m]), as_h(b[n]), acc[m][n], 0, 0, 0);                         \
    }                                                                            \
    __builtin_amdgcn_s_setprio(0);                                               \
    if ((T) < 15) {                                                              \
      if ((T) + 2 < 16) { VM4; } else { VM0; }                                   \
      SB0;                                                                       \
    }                                                                            \
    __builtin_amdgcn_s_barrier();                                                \
  }

    // prologue: stage tiles 0 and 1; [vmcnt(4) -> barrier] lands tile 0.
    issue(0, 1, 0);  issue(0, 0, 0);
    issue(1, 1, 32); issue(1, 0, 32);
    VM4;
    __builtin_amdgcn_s_barrier();

    for (int t = 0; t < 15; t += 3) {
        QK_TILE(t,     0, 2);
        QK_TILE(t + 1, 1, 0);
        QK_TILE(t + 2, 2, 1);
    }
    QK_TILE(15, 0, 2);
#undef QK_TILE

    __syncthreads();
    short* ebuf = &lds[0];
#pragma unroll
    for (int m = 0; m < 4; m++) {
#pragma unroll
        for (int n = 0; n < 4; n++) {
#pragma unroll
            for (int j = 0; j < 4; j++) {
                const int rl = wm + m * 16 + (lane >> 4) * 4 + j;
                const int cl = wn + n * 16 + lrow;
                ebuf[rl * 128 + (cl ^ ((rl & 7) << 3))] =
                    (short)__float2int_rn(acc[m][n][j] * 128.0f);
            }
        }
    }
    __syncthreads();
#pragma unroll
    for (int it = 0; it < 8; it++) {
        const int u = it * 256 + tid;
        const int r = u >> 4, c8 = (u & 15) * 8;
        const s16x8 val = *(const s16x8*)&ebuf[r * 128 + (c8 ^ ((r & 7) << 3))];
        *(s16x8*)&outS[(size_t)(bm + r) * SS + bn + c8] = val;
    }
}

// ---------------------------------------------------------------------------
// Unified projection, all-fp16 1-pass (R18), TRIPLE-buffered counted-vmcnt
// pipeline (same transformation as qkt128). 48 KiB -> 3 blocks/CU.
// ---------------------------------------------------------------------------
__global__ __launch_bounds__(256, 3) void proj_all(
    const short* __restrict__ xh, const short* __restrict__ wt,
    const float* __restrict__ bq, const float* __restrict__ bk,
    const float* __restrict__ bv,
    short* __restrict__ qfp, short* __restrict__ kfp, short* __restrict__ vt)
{
    __shared__ short lds[24576];  // [3 buf][2 arr][4096] = 48 KiB; cbuf reuse

    const int tid = threadIdx.x;
    const int wave = tid >> 6, lane = tid & 63;
    const int flat = blockIdx.x + 12 * blockIdx.y;
    const int w = (flat & 7) * 96 + (flat >> 3);
    const int bxi = w % 12, byi = w / 12;
    const int wsel = bxi >> 2;
    const int bnl = (bxi & 3) * 128;
    const int bm = byi * 128;
    const short* B0 = wt + (size_t)wsel * DD * DD;
    const float* bias = (wsel == 0) ? bq : (wsel == 1) ? bk : bv;

    f32x4 acc[4][4] = {};
    const int wm = (wave >> 1) * 64, wn = (wave & 1) * 64;
    const int lrow = lane & 15, lk16 = (lane >> 4) * 16;

    auto base = [&](int buf, int arr) -> short* { return &lds[(buf * 2 + arr) * 4096]; };
    auto issue = [&](int buf, int arr, int k0) {
#pragma unroll
        for (int h = 0; h < 2; h++) {
            const int Lb = (h << 12) + (tid << 4);
            const int Ls = Lb ^ (((Lb >> 7) & 3) << 4);
            const int row = Ls >> 6, elem = (Ls & 63) >> 1;
            const short* s = arr ? B0 : xh;
            const int rb = arr ? bnl : bm;
            gload_lds16(s + (size_t)(rb + row) * DD + k0 + elem,
                        (char*)base(buf, arr) + Lb);
        }
    };
    auto rd = [&](int buf, int arr, int row) -> s16x8 {
        const int L = (row << 6) + lk16;
        const int Ls = L ^ (((L >> 7) & 3) << 4);
        return *(const s16x8*)((const char*)base(buf, arr) + Ls);
    };

#define PJ_TILE(T, CUR, NX2)                                                     \
  {                                                                              \
    s16x8 a[4], b[4];                                                            \
    _Pragma("unroll")                                                            \
    for (int m = 0; m < 4; m++) a[m] = rd(CUR, 0, wm + m * 16 + lrow);           \
    _Pragma("unroll")                                                            \
    for (int n = 0; n < 4; n++) b[n] = rd(CUR, 1, wn + n * 16 + lrow);           \
    if ((T) + 2 < 16) { issue(NX2, 1, ((T) + 2) * 32); SB0;                      \
                        issue(NX2, 0, ((T) + 2) * 32); }                         \
    LGKM0; SB0;                                                                  \
    __builtin_amdgcn_s_setprio(1);                                               \
    _Pragma("unroll")                                                            \
    for (int m = 0; m < 4; m++) {                                                \
      _Pragma("unroll")                                                          \
      for (int n = 0; n < 4; n++)                                                \
        acc[m][n] = __builtin_amdgcn_mfma_f32_16x16x32_f16(                      \
            as_h(a[m]), as_h(b[n]), acc[m][n], 0, 0, 0);                         \
    }                                                                            \
    __builtin_amdgcn_s_setprio(0);                                               \
    if ((T) < 15) {                                                              \
      if ((T) + 2 < 16) { VM4; } else { VM0; }                                   \
      SB0;                                                                       \
    }                                                                            \
    __builtin_amdgcn_s_barrier();                                                \
  }

    issue(0, 1, 0);  issue(0, 0, 0);
    issue(1, 1, 32); issue(1, 0, 32);
    VM4;
    __builtin_amdgcn_s_barrier();

    for (int t = 0; t < 15; t += 3) {
        PJ_TILE(t,     0, 2);
        PJ_TILE(t + 1, 1, 0);
        PJ_TILE(t + 2, 2, 1);
    }
    PJ_TILE(15, 0, 2);
#undef PJ_TILE

    __syncthreads();
    short* cbuf = &lds[0];  // 32 KiB = 128*128 shorts
#pragma unroll
    for (int m = 0; m < 4; m++) {
#pragma unroll
        for (int n = 0; n < 4; n++) {
#pragma unroll
            for (int j = 0; j < 4; j++) {
                const int rl = wm + m * 16 + (lane >> 4) * 4 + j;
                const int cl = wn + n * 16 + lrow;
                const float v = acc[m][n][j] + bias[bnl + cl];
                if (wsel < 2)
                    cbuf[rl * 128 + (cl ^ ((rl & 7) << 3))] = f2h(v);
                else
                    cbuf[cl * 128 + (rl ^ ((cl & 7) << 3))] = f2h(v);
            }
        }
    }
    __syncthreads();
    if (wsel < 2) {
        short* outp = wsel ? kfp : qfp;
#pragma unroll
        for (int it = 0; it < 8; it++) {
            const int u = it * 256 + tid;
            const int r = u >> 4, c8 = (u & 15) * 8;
            const s16x8 val = *(const s16x8*)&cbuf[r * 128 + (c8 ^ ((r & 7) << 3))];
            *(s16x8*)&outp[(size_t)(bm + r) * DD + bnl + c8] = val;
        }
    } else {
        const int b = bm >> 11, s0 = bm & 2047;
#pragma unroll
        for (int it = 0; it < 8; it++) {
            const int idx = it * 256 + tid;
            const int dd = idx >> 4, c8 = (idx & 15) * 8;
            const s16x8 val = *(const s16x8*)&cbuf[dd * 128 + (c8 ^ ((dd & 7) << 3))];
            *(s16x8*)&vt[((size_t)b << 20) + ((size_t)(bnl + dd) << 11) + s0 + c8] = val;
        }
    }
}

// ---------------------------------------------------------------------------
// PV GEMM fp16: 64x128 tile, BK=64 dbuf, single-phase-per-tile + chunked
// XCD swizzle (R13-proven, unchanged).
// ---------------------------------------------------------------------------
__global__ __launch_bounds__(256, 3) void pv_gemm(
    const short* __restrict__ P, const short* __restrict__ vt,
    float* __restrict__ out, int nwg)
{
    __shared__ short As[2][64 * 64];
    __shared__ short Bs[2][128 * 64];

    const int tid = threadIdx.x;
    const int wave = tid >> 6, lane = tid & 63;
    const int flat = blockIdx.x + 4 * blockIdx.y + 128 * blockIdx.z;
    const int w = (flat & 7) * (nwg >> 3) + (flat >> 3);
    const int bm = ((w >> 2) & 31) * 64, bn = (w & 3) * 128;
    const long z = w >> 7;
    P += z * (long)SS * SS;
    vt += z << 20;
    out += z * (long)SS * DD;

    f32x4 acc[2][4] = {};
    const int wm = (wave >> 1) * 32, wn = (wave & 1) * 64;
    const int lrow = lane & 15, lk = (lane >> 4) * 8;

    auto swz = [](int L) { return L ^ (((L >> 7) & 7) << 4); };
    auto issueA = [&](int buf, int k0) {
#pragma unroll
        for (int h = 0; h < 2; h++) {
            const int L = (h << 12) + (tid << 4);
            const int Ls = swz(L);
            const int row = Ls >> 7, col = (Ls & 127) >> 1;
            gload_lds16(P + (size_t)(bm + row) * SS + k0 + col, (char*)&As[buf][0] + L);
        }
    };
    auto issueB = [&](int buf, int k0) {
#pragma unroll
        for (int h = 0; h < 4; h++) {
            const int L = (h << 12) + (tid << 4);
            const int Ls = swz(L);
            const int row = Ls >> 7, col = (Ls & 127) >> 1;
            gload_lds16(vt + ((size_t)(bn + row) << 11) + k0 + col, (char*)&Bs[buf][0] + L);
        }
    };

#define PV_TILE(T, CUR, PREF)                                                    \
  {                                                                              \
    s16x8 a[2][2], b[2][4];                                                      \
    _Pragma("unroll")                                                            \
    for (int kx = 0; kx < 2; kx++) {                                             \
      _Pragma("unroll")                                                          \
      for (int m = 0; m < 2; m++)                                                \
        a[kx][m] = *(const s16x8*)((const char*)&As[CUR][0] +                    \
                   swz(((wm + m * 16 + lrow) * 64 + kx * 32 + lk) * 2));         \
      _Pragma("unroll")                                                          \
      for (int n = 0; n < 4; n++)                                                \
        b[kx][n] = *(const s16x8*)((const char*)&Bs[CUR][0] +                    \
                   swz(((wn + n * 16 + lrow) * 64 + kx * 32 + lk) * 2));         \
    }                                                                            \
    if (PREF) { issueB((CUR) ^ 1, ((T) + 1) * 64); SB0;                          \
                issueA((CUR) ^ 1, ((T) + 1) * 64); }                             \
    LGKM0; SB0;                                                                  \
    __builtin_amdgcn_s_setprio(1);                                               \
    _Pragma("unroll")                                                            \
    for (int kx = 0; kx < 2; kx++) {                                             \
      _Pragma("unroll")                                                          \
      for (int m = 0; m < 2; m++) {                                              \
        _Pragma("unroll")                                                        \
        for (int n = 0; n < 4; n++)                                              \
          acc[m][n] = __builtin_amdgcn_mfma_f32_16x16x32_f16(                    \
              as_h(a[kx][m]), as_h(b[kx][n]), acc[m][n], 0, 0, 0);               \
      }                                                                          \
    }                                                                            \
    __builtin_amdgcn_s_setprio(0);                                               \
    if (PREF) { VM0; SB0; }                                                      \
    __builtin_amdgcn_s_barrier();                                                \
  }

    issueB(0, 0); issueA(0, 0);
    VM0;
    __builtin_amdgcn_s_barrier();

    for (int t = 0; t < 32; t += 2) {
        PV_TILE(t,     0, 1);
        PV_TILE(t + 1, 1, (t + 1) < 31);
    }
#undef PV_TILE

#pragma unroll
    for (int m = 0; m < 2; m++) {
#pragma unroll
        for (int n = 0; n < 4; n++) {
#pragma unroll
            for (int j = 0; j < 4; j++) {
                const int row = bm + wm + m * 16 + (lane >> 4) * 4 + j;
                const int col = bn + wn + n * 16 + lrow;
                out[(size_t)row * DD + col] = acc[m][n][j];
            }
        }
    }
}

// merged casts (R18, unchanged)
__global__ __launch_bounds__(256) void cast_all(
    const float* __restrict__ x,
    const float* __restrict__ wq, const float* __restrict__ wk,
    const float* __restrict__ wv,
    short* __restrict__ xh, short* __restrict__ wt)
{
    const int bid = blockIdx.x;
    if (bid < 4096) {
        const int i = bid * 256 + threadIdx.x;
        const float4 v = ((const float4*)x)[i];
        const float vv[4] = {v.x, v.y, v.z, v.w};
        s16x4 h;
#pragma unroll
        for (int j = 0; j < 4; j++) h[j] = f2h(vv[j]);
        ((s16x4*)xh)[i] = h;
    } else {
        const int t = (bid - 4096) * 256 + threadIdx.x;
        const int w = t >> 18;
        const int r = t & 262143;
        const float* src = (w == 0) ? wq : ((w == 1) ? wk : wv);
        const float v = src[r];
        const int k = r >> 9, n = r & 511;
        wt[((size_t)w << 18) + ((size_t)n << 9) + k] = f2h(v);
    }
}

// softmax over int16 scores (scale 1/128), fp16 P out (unchanged)
__global__ __launch_bounds__(256) void softmax_rows(
    const short* __restrict__ S, short* __restrict__ P)
{
    const int row = blockIdx.x;
    const long z = blockIdx.y;
    const short* s = S + z * (long)SS * SS + (long)row * SS;
    short* p = P + z * (long)SS * SS + (long)row * SS;
    const int tid = threadIdx.x;

    const s16x8 raw = ((const s16x8*)s)[tid];
    float v[8];
#pragma unroll
    for (int j = 0; j < 8; j++) v[j] = (float)(int)raw[j] * 0.0078125f;

    float m = v[0];
#pragma unroll
    for (int j = 1; j < 8; j++) m = fmaxf(m, v[j]);
#pragma unroll
    for (int off = 32; off >= 1; off >>= 1) m = fmaxf(m, __shfl_xor(m, off));
    __shared__ float redm[4], reds[4];
    if ((tid & 63) == 0) redm[tid >> 6] = m;
    __syncthreads();
    m = fmaxf(fmaxf(redm[0], redm[1]), fmaxf(redm[2], redm[3]));

    float e[8], sum = 0.f;
#pragma unroll
    for (int j = 0; j < 8; j++) { e[j] = __expf(v[j] - m); sum += e[j]; }
#pragma unroll
    for (int off = 32; off >= 1; off >>= 1) sum += __shfl_xor(sum, off);
    if ((tid & 63) == 0) reds[tid >> 6] = sum;
    __syncthreads();
    sum = reds[0] + reds[1] + reds[2] + reds[3];
    const float inv = 1.0f / sum;

    s16x8 o;
#pragma unroll
    for (int j = 0; j < 8; j++) o[j] = f2h(e[j] * inv);
    ((s16x8*)p)[tid] = o;
}

extern "C" void kernel_launch(void* const* d_in, const int* in_sizes, int n_in,
                              void* d_out, int out_size, void* d_ws, size_t ws_size,
                              hipStream_t stream)
{
    const float* x  = (const float*)d_in[0];
    const float* Wq = (const float*)d_in[1];
    const float* Wk = (const float*)d_in[2];
    const float* Wv = (const float*)d_in[3];
    const float* bq = (const float*)d_in[4];
    const float* bk = (const float*)d_in[5];
    const float* bv = (const float*)d_in[6];
    float* out = (float*)d_out;

    const size_t MK = (size_t)BB * SS * DD;
    char* ws = (char*)d_ws;
    short* xh  = (short*)ws; ws += MK * 2;
    short* wt  = (short*)ws; ws += 3ull * DD * DD * 2;
    short* qfp = (short*)ws; ws += MK * 2;
    short* kfp = (short*)ws; ws += MK * 2;
    short* vt  = (short*)ws; ws += MK * 2;
    const size_t fixed = (size_t)(ws - (char*)d_ws);

    int g = 4;
    while (g > 0 && fixed + (size_t)g * ((size_t)SS * SS * 2 + (size_t)SS * SS * 2) > ws_size)
        g >>= 1;
    if (g == 0) return;
    short* sc = (short*)ws;
    short* P  = (short*)(ws + (size_t)g * SS * SS * 2);

    cast_all<<<dim3(7168), 256, 0, stream>>>(x, Wq, Wk, Wv, xh, wt);
    proj_all<<<dim3(12, 64), 256, 0, stream>>>(xh, wt, bq, bk, bv,
                                               qfp, kfp, vt);

    for (int b0 = 0; b0 < BB; b0 += g) {
        const int gg = (b0 + g <= BB) ? g : (BB - b0);
        qkt128<<<dim3(16, 16, gg), 256, 0, stream>>>(
            qfp + (size_t)b0 * SS * DD, kfp + (size_t)b0 * SS * DD, sc, 256 * gg);
        softmax_rows<<<dim3(SS, gg), 256, 0, stream>>>(sc, P);
        pv_gemm<<<dim3(4, 32, gg), 256, 0, stream>>>(
            P, vt + ((size_t)b0 << 20), out + (size_t)b0 * SS * DD, 128 * gg);
    }
}